// Round 13
// baseline (1230.811 us; speedup 1.0000x reference)
//
#include <hip/hip_runtime.h>
#include <hip/hip_bf16.h>

typedef float f32x4 __attribute__((ext_vector_type(4)));
typedef short s16x8 __attribute__((ext_vector_type(8)));

#define REP_PREP 48
#define REP_MID  6
#define REP_ATTN 16
#define REP_OUT  64

__device__ __forceinline__ unsigned short f2bf(float x){
  unsigned u = __float_as_uint(x);
  u += 0x7fffu + ((u >> 16) & 1u);
  return (unsigned short)(u >> 16);
}
__device__ __forceinline__ float bf2f(unsigned short h){
  return __uint_as_float(((unsigned)h) << 16);
}
__device__ __forceinline__ unsigned pk_bf(float a, float b){
  __hip_bfloat162 t = __float22bfloat162_rn(make_float2(a, b));
  return *reinterpret_cast<unsigned*>(&t);
}

// ---- prep: weight transpose->bf16 (0..179), ln_a (180..435), setup (436), zero-pads (437..628) ----
__global__ __launch_bounds__(256) void prep_kernel(const float* __restrict__ a, const float* __restrict__ ln_a_w,
                             const float* __restrict__ ln_a_b, const float* __restrict__ lnzw,
                             const float* __restrict__ lnzb, const float* __restrict__ w_z,
                             const float* __restrict__ wq, const float* __restrict__ wk,
                             const float* __restrict__ wv, const float* __restrict__ wg,
                             const float* __restrict__ wo,
                             unsigned short* __restrict__ a_lnB, unsigned short* __restrict__ wBall,
                             unsigned short* __restrict__ wwB, float* __restrict__ TU,
                             unsigned short* __restrict__ qTp, unsigned short* __restrict__ kTp,
                             unsigned short* __restrict__ vTt, long roff){
  int bid = blockIdx.x, tid = threadIdx.x;
  if (bid < 180){
    __shared__ float t[64][65];
    int mat = bid/36, tt = bid - mat*36;
    int c0 = (tt % 6)*64, k0 = (tt / 6)*64;
    const float* src0 = mat == 0 ? wq : mat == 1 ? wk : mat == 2 ? wv : mat == 3 ? wg : wo;
    for (int rep = 0; rep < REP_PREP; ++rep){
      const float* src = src0 + (size_t)rep*roff;
      int r = tid >> 4, c4 = (tid & 15)*4;
      #pragma unroll
      for (int rr = 0; rr < 4; ++rr){
        float4 v = *(const float4*)(src + (size_t)(k0 + r + rr*16)*384 + c0 + c4);
        t[r + rr*16][c4+0] = v.x; t[r + rr*16][c4+1] = v.y;
        t[r + rr*16][c4+2] = v.z; t[r + rr*16][c4+3] = v.w;
      }
      __syncthreads();
      float scale = (mat == 0) ? 0.20412414523193154f : 1.f;
      int cc = tid >> 2, kp = (tid & 3)*16;
      unsigned ow[8];
      #pragma unroll
      for (int j = 0; j < 8; ++j)
        ow[j] = pk_bf(t[kp + 2*j][cc]*scale, t[kp + 2*j + 1][cc]*scale);
      unsigned short* dst = wBall + ((size_t)(mat*384 + c0 + cc)*384 + k0 + kp);
      *(uint4*)dst       = make_uint4(ow[0], ow[1], ow[2], ow[3]);
      *(uint4*)(dst + 8) = make_uint4(ow[4], ow[5], ow[6], ow[7]);
      __syncthreads();
    }
  } else if (bid < 436){
    for (int rep = 0; rep < REP_PREP; ++rep){
      const float* ab = a + (size_t)rep*roff;
      int r = (bid - 180)*4 + (tid >> 6), l = tid & 63;
      const float* ap = ab + (size_t)r*384;
      float x[6]; float s = 0.f, sq = 0.f;
      #pragma unroll
      for (int i = 0; i < 6; ++i){ x[i] = ap[i*64 + l]; s += x[i]; sq += x[i]*x[i]; }
      #pragma unroll
      for (int off = 32; off; off >>= 1){ s += __shfl_xor(s, off); sq += __shfl_xor(sq, off); }
      float mu = s*(1.f/384.f);
      float var = sq*(1.f/384.f) - mu*mu;
      float rs = rsqrtf(var + 1e-5f);
      #pragma unroll
      for (int i = 0; i < 6; ++i){ int c = i*64 + l; a_lnB[(size_t)r*384 + c] = f2bf((x[i]-mu)*rs*ln_a_w[c] + ln_a_b[c]); }
    }
  } else if (bid == 436){
    for (int rep = 0; rep < REP_PREP; ++rep){
      const float* zw = lnzw + (size_t)rep*roff;
      if (tid < 128){
        float lw = zw[tid];
        #pragma unroll
        for (int h = 0; h < 16; ++h) wwB[tid*16 + h] = f2bf(lw * w_z[tid*16 + h]);
      }
      if (tid < 16){
        float T = 0.f, U = 0.f;
        for (int c = 0; c < 128; ++c){ T += zw[c]*w_z[c*16 + tid]; U += lnzb[c]*w_z[c*16 + tid]; }
        TU[tid] = T; TU[16 + tid] = U;
      }
    }
  } else {
    int t = (bid - 437)*256 + tid;       // 0..49151
    uint4 zv = make_uint4(0,0,0,0);
    if (t < 16384)      *(uint4*)(qTp + (size_t)t*32 + 24) = zv;
    else if (t < 32768) *(uint4*)(kTp + (size_t)(t - 16384)*32 + 24) = zv;
    else {
      int t2 = t - 32768;                 // 0..16383
      int h = t2 >> 10, w = t2 & 1023;
      *(uint4*)(vTt + ((size_t)h*32 + 24)*1024 + (size_t)w*8) = zv;
    }
  }
}

// ---- fused mid: blocks 0..383 = QKVG MFMA; blocks 384..4479 = zbias ----
__global__ __launch_bounds__(256) void midfuse_kernel(const unsigned short* __restrict__ AB,
                                                      const unsigned short* __restrict__ wBt,
                                                      const float* __restrict__ bg,
                                                      unsigned short* __restrict__ qTp, unsigned short* __restrict__ kTp,
                                                      unsigned short* __restrict__ vTt, float* __restrict__ g,
                                                      const float* __restrict__ z, const unsigned short* __restrict__ wwB,
                                                      const float* __restrict__ TU, const float* __restrict__ mask,
                                                      unsigned short* __restrict__ pbM, long roff){
  __shared__ char smem[16384];
  int bid = blockIdx.x, tid = threadIdx.x;
  int wave = tid >> 6, lane = tid & 63, l15 = lane & 15, sub = lane >> 4;
  if (bid < 384){
    // ---------------- QKVG ----------------
    s16x8* Al8 = (s16x8*)smem;
    s16x8* Bl8 = (s16x8*)(smem + 8192);
    int bx = bid % 24, by = bid / 24;
    int n0 = bx*64, m0 = by*64;
    for (int rep = 0; rep < REP_MID; ++rep){
      const s16x8* Ag = (const s16x8*)(AB + (size_t)rep*roff);
      const s16x8* Bg = (const s16x8*)(wBt + (size_t)rep*roff);
      f32x4 acc[4];
      #pragma unroll
      for (int c = 0; c < 4; ++c) acc[c] = (f32x4){0.f,0.f,0.f,0.f};
      for (int ks = 0; ks < 6; ++ks){
        int k0u = ks*8;
        #pragma unroll
        for (int j = 0; j < 2; ++j){
          int idx = tid*2 + j;
          int row = idx >> 3, u = idx & 7;
          Al8[row*8 + (u ^ (row & 7))] = Ag[(size_t)(m0 + row)*48 + k0u + u];
          Bl8[row*8 + (u ^ (row & 7))] = Bg[(size_t)(n0 + row)*48 + k0u + u];
        }
        __syncthreads();
        #pragma unroll
        for (int kk = 0; kk < 2; ++kk){
          int arow = wave*16 + l15;
          s16x8 af = Al8[arow*8 + ((kk*4 + sub) ^ (arow & 7))];
          #pragma unroll
          for (int c = 0; c < 4; ++c){
            int brow = c*16 + l15;
            s16x8 bf = Bl8[brow*8 + ((kk*4 + sub) ^ (brow & 7))];
            acc[c] = __builtin_amdgcn_mfma_f32_16x16x32_bf16(af, bf, acc[c], 0, 0, 0);
          }
        }
        __syncthreads();
      }
      int which = bx / 6;
      int cb = n0 - which*384;
      if (which == 3){
        #pragma unroll
        for (int c = 0; c < 4; ++c){
          int col = cb + c*16 + l15;
          #pragma unroll
          for (int r = 0; r < 4; ++r){
            int row = m0 + wave*16 + sub*4 + r;
            float t = acc[c][r] + bg[col];
            g[(size_t)row*384 + col] = 1.f/(1.f + __expf(-t));
          }
        }
      } else if (which == 2){
        #pragma unroll
        for (int c = 0; c < 4; ++c){
          int col = cb + c*16 + l15;
          int h = col/24, d = col - h*24;
          unsigned p0 = pk_bf(acc[c][0], acc[c][1]);
          unsigned p1 = pk_bf(acc[c][2], acc[c][3]);
          size_t base = ((size_t)h*32 + d)*1024 + (size_t)(m0 + wave*16 + sub*4);
          *(uint2*)(vTt + base) = make_uint2(p0, p1);
        }
      } else {
        unsigned short* dst = which == 0 ? qTp : kTp;
        #pragma unroll
        for (int c = 0; c < 4; ++c){
          int col = cb + c*16 + l15;
          int h = col/24, d = col - h*24;
          #pragma unroll
          for (int r = 0; r < 4; ++r){
            int row = m0 + wave*16 + sub*4 + r;
            dst[((size_t)(h << 10) + row)*32 + d] = f2bf(acc[c][r]);
          }
        }
      }
    }
  } else {
    // ---------------- zbias ----------------
    float* sums = (float*)smem;
    float* sqs  = sums + 64;
    float (*accT)[17] = (float(*)[17])(sqs + 64);
    int tb = bid - 384;
    int h = l15, subz = sub;
    s16x8 bfr[4];
    #pragma unroll
    for (int kc = 0; kc < 4; ++kc)
      #pragma unroll
      for (int j = 0; j < 8; ++j) bfr[kc][j] = (short)wwB[(kc*32 + subz*8 + j)*16 + h];
    s16x8 ones1;
    #pragma unroll
    for (int j = 0; j < 8; ++j) ones1[j] = (h == 0) ? (short)0x3F80 : (short)0;
    int eh = tid >> 4, epl0 = (tid & 15)*4;
    float Te = TU[eh], Ue = TU[16 + eh];
    int row = wave*16 + h;
    for (int rep = 0; rep < REP_MID; ++rep){
    const float* zr = z + (size_t)rep*roff;
    for (int it = 0; it < 4; ++it){
      int tile = tb + it*4096;
      size_t pairBase = (size_t)tile*64;
      const float* zrow = zr + (pairBase + row)*128;
      f32x4 acc  = {0.f, 0.f, 0.f, 0.f};
      f32x4 accS = {0.f, 0.f, 0.f, 0.f};
      f32x4 accG = {0.f, 0.f, 0.f, 0.f};
      #pragma unroll
      for (int kc = 0; kc < 4; ++kc){
        f32x4 v0 = *(const f32x4*)(zrow + kc*32 + subz*8);
        f32x4 v1 = *(const f32x4*)(zrow + kc*32 + subz*8 + 4);
        union { unsigned u[4]; s16x8 s; } cv;
        cv.u[0] = pk_bf(v0.x, v0.y); cv.u[1] = pk_bf(v0.z, v0.w);
        cv.u[2] = pk_bf(v1.x, v1.y); cv.u[3] = pk_bf(v1.z, v1.w);
        s16x8 af = cv.s;
        acc  = __builtin_amdgcn_mfma_f32_16x16x32_bf16(af, bfr[kc], acc, 0, 0, 0);
        accS = __builtin_amdgcn_mfma_f32_16x16x32_bf16(af, ones1, accS, 0, 0, 0);
        accG = __builtin_amdgcn_mfma_f32_16x16x32_bf16(af, af, accG, 0, 0, 0);
      }
      #pragma unroll
      for (int r = 0; r < 4; ++r) accT[wave*16 + subz*4 + r][h] = acc[r];
      if (h == 0){
        #pragma unroll
        for (int r = 0; r < 4; ++r) sums[wave*16 + subz*4 + r] = accS[r];
      }
      if (subz == (h >> 2)){
        int r = h & 3;
        float vq = r == 0 ? accG[0] : r == 1 ? accG[1] : r == 2 ? accG[2] : accG[3];
        sqs[wave*16 + h] = vq;
      }
      __syncthreads();
      float mus[4], rss[4];
      #pragma unroll
      for (int rr = 0; rr < 4; ++rr){
        float mu = sums[epl0+rr]*(1.f/128.f);
        float var = sqs[epl0+rr]*(1.f/128.f) - mu*mu;
        mus[rr] = mu; rss[rr] = rsqrtf(var + 1e-5f);
      }
      size_t p0 = pairBase + epl0;
      int q = (int)(p0 >> 10), k0 = (int)(p0 & 1023);
      float4 mk = *(const float4*)(mask + k0);
      float bv[4];
      bv[0] = rss[0]*(accT[epl0+0][eh] - mus[0]*Te) + Ue + 1e9f*(mk.x - 1.f);
      bv[1] = rss[1]*(accT[epl0+1][eh] - mus[1]*Te) + Ue + 1e9f*(mk.y - 1.f);
      bv[2] = rss[2]*(accT[epl0+2][eh] - mus[2]*Te) + Ue + 1e9f*(mk.z - 1.f);
      bv[3] = rss[3]*(accT[epl0+3][eh] - mus[3]*Te) + Ue + 1e9f*(mk.w - 1.f);
      int qb = q >> 6, q64 = q & 63;
      int qg = q64 >> 4, subq = (q64 >> 2) & 3, rr2 = q64 & 3;
      int kkt = k0 >> 6, c = (k0 >> 4) & 3, l15k = k0 & 15;
      size_t cbase = ((((size_t)(eh*16 + qb)*16 + kkt)*4 + qg)*4 + c)*256 + (size_t)rr2;
      #pragma unroll
      for (int i = 0; i < 4; ++i)
        pbM[cbase + (size_t)(subq*16 + l15k + i)*4] = f2bf(bv[i]);
      __syncthreads();
    }
    }
  }
}

// ---- attn v8: MFMA flash. block=(qb32,h) 512 blocks, 8 waves = 2 q-groups x 4 kk-quarters ----
__global__ __launch_bounds__(512) void attn_kernel(const unsigned short* __restrict__ qTp, const unsigned short* __restrict__ kTp,
                                                   const unsigned short* __restrict__ vTt, const unsigned short* __restrict__ pbM,
                                                   const float* __restrict__ g, unsigned short* __restrict__ ogB, long roff){
  __shared__ float lds[8192];          // 8 waves x 1024 floats: P tile / state
  int tid = threadIdx.x;
  int wave = tid >> 6, lane = tid & 63, l15 = lane & 15, sub = lane >> 4;
  int qb32 = blockIdx.x, h = blockIdx.y;
  int qg_l = wave & 1, kkq = wave >> 1;
  int qrow = qb32*32 + qg_l*16 + l15;
  char* Pb = (char*)(lds + wave*1024);
  int qb64 = qb32 >> 1, qg4 = (qb32 & 1)*2 + qg_l;
  for (int rep = 0; rep < REP_ATTN; ++rep){
    const unsigned short* qTr = qTp + (size_t)rep*roff;
    const unsigned short* kBase = kTp + (size_t)rep*roff + ((size_t)(h << 10))*32;
    const unsigned short* vBase = vTt + (size_t)rep*roff + (size_t)h*32*1024;
    const unsigned short* pbW = pbM + (size_t)rep*roff + (size_t)(h*16 + qb64)*16*4096 + (size_t)qg4*1024 + (size_t)lane*4;
    s16x8 qf = *(const s16x8*)(qTr + ((size_t)(h << 10) + qrow)*32 + sub*8);
    f32x4 o0 = {0.f,0.f,0.f,0.f}, o1 = {0.f,0.f,0.f,0.f};
    float m[4] = {-1e30f,-1e30f,-1e30f,-1e30f}, l[4] = {0.f,0.f,0.f,0.f};
    for (int t = 0; t < 4; ++t){
      int kkt = kkq*4 + t;
      int kk0 = kkt*64;
      const unsigned short* pbt = pbW + (size_t)kkt*4096;
      uint2 pv0 = *(const uint2*)(pbt + 0);
      uint2 pv1 = *(const uint2*)(pbt + 256);
      uint2 pv2 = *(const uint2*)(pbt + 512);
      uint2 pv3 = *(const uint2*)(pbt + 768);
      f32x4 s[4];
      #pragma unroll
      for (int c = 0; c < 4; ++c){
        s16x8 kf = *(const s16x8*)(kBase + (size_t)(kk0 + c*16 + l15)*32 + sub*8);
        s[c] = __builtin_amdgcn_mfma_f32_16x16x32_bf16(qf, kf, (f32x4){0.f,0.f,0.f,0.f}, 0, 0, 0);
      }
      {
        uint2 pv[4] = {pv0, pv1, pv2, pv3};
        #pragma unroll
        for (int c = 0; c < 4; ++c){
          s[c][0] += bf2f((unsigned short)(pv[c].x & 0xffff));
          s[c][1] += bf2f((unsigned short)(pv[c].x >> 16));
          s[c][2] += bf2f((unsigned short)(pv[c].y & 0xffff));
          s[c][3] += bf2f((unsigned short)(pv[c].y >> 16));
        }
      }
      #pragma unroll
      for (int r = 0; r < 4; ++r){
        float pm = fmaxf(fmaxf(s[0][r], s[1][r]), fmaxf(s[2][r], s[3][r]));
        pm = fmaxf(pm, __shfl_xor(pm, 1));
        pm = fmaxf(pm, __shfl_xor(pm, 2));
        pm = fmaxf(pm, __shfl_xor(pm, 4));
        pm = fmaxf(pm, __shfl_xor(pm, 8));
        float mn = fmaxf(m[r], pm);
        float corr = __expf(m[r] - mn);
        m[r] = mn;
        float ps = 0.f;
        #pragma unroll
        for (int c = 0; c < 4; ++c){ s[c][r] = __expf(s[c][r] - mn); ps += s[c][r]; }
        ps += __shfl_xor(ps, 1); ps += __shfl_xor(ps, 2);
        ps += __shfl_xor(ps, 4); ps += __shfl_xor(ps, 8);
        l[r] = l[r]*corr + ps;
        o0[r] *= corr; o1[r] *= corr;
      }
      #pragma unroll
      for (int c = 0; c < 4; ++c){
        #pragma unroll
        for (int r = 0; r < 4; ++r){
          int qq = sub*4 + r;
          int byte = ((qq*128 + (c*16 + l15)*2)) ^ ((qq & 7) << 4);
          *(short*)(Pb + byte) = (short)f2bf(s[c][r]);
        }
      }
      #pragma unroll
      for (int kh = 0; kh < 2; ++kh){
        int byteA = (l15*128 + kh*64 + sub*16) ^ ((l15 & 7) << 4);
        s16x8 pa = *(const s16x8*)(Pb + byteA);
        s16x8 vb0 = *(const s16x8*)(vBase + (size_t)l15*1024 + kk0 + kh*32 + sub*8);
        s16x8 vb1 = *(const s16x8*)(vBase + (size_t)(16 + l15)*1024 + kk0 + kh*32 + sub*8);
        o0 = __builtin_amdgcn_mfma_f32_16x16x32_bf16(pa, vb0, o0, 0, 0, 0);
        o1 = __builtin_amdgcn_mfma_f32_16x16x32_bf16(pa, vb1, o1, 0, 0, 0);
      }
    }
    {
      float* cw = lds + wave*1024 + lane*16;
      cw[0] = o0[0]; cw[1] = o0[1]; cw[2] = o0[2]; cw[3] = o0[3];
      cw[4] = o1[0]; cw[5] = o1[1]; cw[6] = o1[2]; cw[7] = o1[3];
      cw[8] = m[0]; cw[9] = m[1]; cw[10] = m[2]; cw[11] = m[3];
      cw[12] = l[0]; cw[13] = l[1]; cw[14] = l[2]; cw[15] = l[3];
    }
    __syncthreads();
    if (kkq == 0){
      #pragma unroll
      for (int k2 = 1; k2 < 4; ++k2){
        const float* c2 = lds + (size_t)(k2*2 + qg_l)*1024 + lane*16;
        #pragma unroll
        for (int r = 0; r < 4; ++r){
          float m2 = c2[8 + r], l2 = c2[12 + r];
          float nm = fmaxf(m[r], m2);
          float f1 = __expf(m[r] - nm), f2 = __expf(m2 - nm);
          l[r] = l[r]*f1 + l2*f2;
          o0[r] = o0[r]*f1 + c2[r]*f2;
          o1[r] = o1[r]*f1 + c2[4 + r]*f2;
          m[r] = nm;
        }
      }
      #pragma unroll
      for (int r = 0; r < 4; ++r){
        float inv = 1.f/l[r];
        int q = qb32*32 + qg_l*16 + sub*4 + r;
        size_t base = (size_t)q*384 + h*24;
        ogB[base + l15] = f2bf(g[base + l15]*o0[r]*inv);
        if (l15 < 8) ogB[base + 16 + l15] = f2bf(g[base + 16 + l15]*o1[r]*inv);
      }
    }
    __syncthreads();
  }
}

// ---- final projection: ogB[1024x384]bf16 @ wo^T bf16 via MFMA, + bo ----
__global__ __launch_bounds__(256) void gemm_out(const unsigned short* __restrict__ AB,
                                                const unsigned short* __restrict__ wBo,
                                                const float* __restrict__ bo, float* __restrict__ dst, long roff){
  __shared__ short Al[64*8*8];
  __shared__ short Bl[64*8*8];
  int tid = threadIdx.x;
  int wave = tid >> 6, lane = tid & 63, l15 = lane & 15, sub = lane >> 4;
  int n0 = blockIdx.x*64, m0 = blockIdx.y*64;
  s16x8* Al8 = (s16x8*)Al; s16x8* Bl8 = (s16x8*)Bl;
  for (int rep = 0; rep < REP_OUT; ++rep){
    const s16x8* Ag = (const s16x8*)(AB + (size_t)rep*roff);
    const s16x8* Bg = (const s16x8*)(wBo + (size_t)rep*roff);
    f32x4 acc[4];
    #pragma unroll
    for (int c = 0; c < 4; ++c) acc[c] = (f32x4){0.f,0.f,0.f,0.f};
    for (int ks = 0; ks < 6; ++ks){
      int k0u = ks*8;
      #pragma unroll
      for (int j = 0; j < 2; ++j){
        int idx = tid*2 + j;
        int row = idx >> 3, u = idx & 7;
        Al8[row*8 + (u ^ (row & 7))] = Ag[(size_t)(m0 + row)*48 + k0u + u];
        Bl8[row*8 + (u ^ (row & 7))] = Bg[(size_t)(n0 + row)*48 + k0u + u];
      }
      __syncthreads();
      #pragma unroll
      for (int kk = 0; kk < 2; ++kk){
        int arow = wave*16 + l15;
        s16x8 af = Al8[arow*8 + ((kk*4 + sub) ^ (arow & 7))];
        #pragma unroll
        for (int c = 0; c < 4; ++c){
          int brow = c*16 + l15;
          s16x8 bf = Bl8[brow*8 + ((kk*4 + sub) ^ (brow & 7))];
          acc[c] = __builtin_amdgcn_mfma_f32_16x16x32_bf16(af, bf, acc[c], 0, 0, 0);
        }
      }
      __syncthreads();
    }
    #pragma unroll
    for (int c = 0; c < 4; ++c){
      int col = n0 + c*16 + l15;
      float b = bo[col];
      #pragma unroll
      for (int r = 0; r < 4; ++r){
        int row = m0 + wave*16 + sub*4 + r;
        dst[(size_t)row*384 + col] = acc[c][r] + b;
      }
    }
  }
}

extern "C" void kernel_launch(void* const* d_in, const int* in_sizes, int n_in,
                              void* d_out, int out_size, void* d_ws, size_t ws_size,
                              hipStream_t stream){
  const float* a      = (const float*)d_in[0];
  const float* z      = (const float*)d_in[1];
  const float* mask   = (const float*)d_in[2];
  const float* ln_a_w = (const float*)d_in[3];
  const float* ln_a_b = (const float*)d_in[4];
  const float* ln_z_w = (const float*)d_in[5];
  const float* ln_z_b = (const float*)d_in[6];
  const float* w_z    = (const float*)d_in[7];
  const float* wq     = (const float*)d_in[8];
  const float* wk     = (const float*)d_in[9];
  const float* wv     = (const float*)d_in[10];
  const float* wg     = (const float*)d_in[11];
  const float* bg     = (const float*)d_in[12];
  const float* wo     = (const float*)d_in[13];
  const float* bo     = (const float*)d_in[14];

  char* ws = (char*)d_ws;
  unsigned short* a_lnB = (unsigned short*)(ws + ((size_t)0u));
  unsigned short* wBall = (unsigned short*)(ws + ((size_t)1u << 20));
  unsigned short* qTp   = (unsigned short*)(ws + ((size_t)4u << 20));
  unsigned short* kTp   = (unsigned short*)(ws + ((size_t)6u << 20));
  unsigned short* vTt   = (unsigned short*)(ws + ((size_t)8u << 20));
  float* g    = (float*)(ws + ((size_t)10u << 20));
  unsigned short* ogB = (unsigned short*)(ws + ((size_t)12u << 20));
  unsigned short* wwB = (unsigned short*)(ws + ((size_t)14u << 20));
  float* TU   = (float*)(ws + ((size_t)14u << 20) + 8192);
  unsigned short* pbM = (unsigned short*)(ws + ((size_t)24u << 20));

  long roff = 0;
  hipLaunchKernelGGL(prep_kernel, dim3(629), dim3(256), 0, stream, a, ln_a_w, ln_a_b,
                     ln_z_w, ln_z_b, w_z, wq, wk, wv, wg, wo, a_lnB, wBall, wwB, TU, qTp, kTp, vTt, roff);
  hipLaunchKernelGGL(midfuse_kernel, dim3(4480), dim3(256), 0, stream, a_lnB, wBall, bg,
                     qTp, kTp, vTt, g, z, wwB, TU, mask, pbM, roff);
  hipLaunchKernelGGL(attn_kernel, dim3(32,16), dim3(512), 0, stream, qTp, kTp, vTt, pbM, g, ogB, roff);
  hipLaunchKernelGGL(gemm_out, dim3(6,16), dim3(256), 0, stream, ogB, wBall + (size_t)4*384*384, bo, (float*)d_out, roff);
}

// Round 14
// 161.474 us; speedup vs baseline: 7.6223x; 7.6223x over previous
//
#include <hip/hip_runtime.h>
#include <hip/hip_bf16.h>

typedef float f32x4 __attribute__((ext_vector_type(4)));
typedef short s16x8 __attribute__((ext_vector_type(8)));

__device__ __forceinline__ unsigned short f2bf(float x){
  unsigned u = __float_as_uint(x);
  u += 0x7fffu + ((u >> 16) & 1u);
  return (unsigned short)(u >> 16);
}
__device__ __forceinline__ float bf2f(unsigned short h){
  return __uint_as_float(((unsigned)h) << 16);
}
__device__ __forceinline__ unsigned pk_bf(float a, float b){
  __hip_bfloat162 t = __float22bfloat162_rn(make_float2(a, b));
  return *reinterpret_cast<unsigned*>(&t);
}

// ---- prep: weight transpose->bf16 (0..179), ln_a (180..435), setup (436), zero-pads (437..628) ----
__global__ __launch_bounds__(256) void prep_kernel(const float* __restrict__ a, const float* __restrict__ ln_a_w,
                             const float* __restrict__ ln_a_b, const float* __restrict__ lnzw,
                             const float* __restrict__ lnzb, const float* __restrict__ w_z,
                             const float* __restrict__ wq, const float* __restrict__ wk,
                             const float* __restrict__ wv, const float* __restrict__ wg,
                             const float* __restrict__ wo,
                             unsigned short* __restrict__ a_lnB, unsigned short* __restrict__ wBall,
                             unsigned short* __restrict__ wwB, float* __restrict__ TU,
                             unsigned short* __restrict__ qTp, unsigned short* __restrict__ kTp,
                             unsigned short* __restrict__ vTt){
  int bid = blockIdx.x, tid = threadIdx.x;
  if (bid < 180){
    __shared__ float t[64][65];
    int mat = bid/36, tt = bid - mat*36;
    int c0 = (tt % 6)*64, k0 = (tt / 6)*64;
    const float* src = mat == 0 ? wq : mat == 1 ? wk : mat == 2 ? wv : mat == 3 ? wg : wo;
    int r = tid >> 4, c4 = (tid & 15)*4;
    #pragma unroll
    for (int rr = 0; rr < 4; ++rr){
      float4 v = *(const float4*)(src + (size_t)(k0 + r + rr*16)*384 + c0 + c4);
      t[r + rr*16][c4+0] = v.x; t[r + rr*16][c4+1] = v.y;
      t[r + rr*16][c4+2] = v.z; t[r + rr*16][c4+3] = v.w;
    }
    __syncthreads();
    float scale = (mat == 0) ? 0.20412414523193154f : 1.f;
    int cc = tid >> 2, kp = (tid & 3)*16;
    unsigned ow[8];
    #pragma unroll
    for (int j = 0; j < 8; ++j)
      ow[j] = pk_bf(t[kp + 2*j][cc]*scale, t[kp + 2*j + 1][cc]*scale);
    unsigned short* dst = wBall + ((size_t)(mat*384 + c0 + cc)*384 + k0 + kp);
    *(uint4*)dst       = make_uint4(ow[0], ow[1], ow[2], ow[3]);
    *(uint4*)(dst + 8) = make_uint4(ow[4], ow[5], ow[6], ow[7]);
  } else if (bid < 436){
    int r = (bid - 180)*4 + (tid >> 6), l = tid & 63;
    const float* ap = a + (size_t)r*384;
    float x[6]; float s = 0.f, sq = 0.f;
    #pragma unroll
    for (int i = 0; i < 6; ++i){ x[i] = ap[i*64 + l]; s += x[i]; sq += x[i]*x[i]; }
    #pragma unroll
    for (int off = 32; off; off >>= 1){ s += __shfl_xor(s, off); sq += __shfl_xor(sq, off); }
    float mu = s*(1.f/384.f);
    float var = sq*(1.f/384.f) - mu*mu;
    float rs = rsqrtf(var + 1e-5f);
    #pragma unroll
    for (int i = 0; i < 6; ++i){ int c = i*64 + l; a_lnB[(size_t)r*384 + c] = f2bf((x[i]-mu)*rs*ln_a_w[c] + ln_a_b[c]); }
  } else if (bid == 436){
    if (tid < 128){
      float lw = lnzw[tid];
      #pragma unroll
      for (int h = 0; h < 16; ++h) wwB[tid*16 + h] = f2bf(lw * w_z[tid*16 + h]);
    }
    if (tid < 16){
      float T = 0.f, U = 0.f;
      for (int c = 0; c < 128; ++c){ T += lnzw[c]*w_z[c*16 + tid]; U += lnzb[c]*w_z[c*16 + tid]; }
      TU[tid] = T; TU[16 + tid] = U;
    }
  } else {
    int t = (bid - 437)*256 + tid;       // 0..49151
    uint4 zv = make_uint4(0,0,0,0);
    if (t < 16384)      *(uint4*)(qTp + (size_t)t*32 + 24) = zv;
    else if (t < 32768) *(uint4*)(kTp + (size_t)(t - 16384)*32 + 24) = zv;
    else {
      int t2 = t - 32768;                 // 0..16383
      int h = t2 >> 10, w = t2 & 1023;
      *(uint4*)(vTt + ((size_t)h*32 + 24)*1024 + (size_t)w*8) = zv;
    }
  }
}

// ---- fused QKVG MFMA: emits qTp/kTp bf16 [h][1024][32], vTt bf16 [h][32][1024], g f32 ----
__global__ __launch_bounds__(256) void qkvg_kernel(const unsigned short* __restrict__ AB,
                                                   const unsigned short* __restrict__ wBt,
                                                   const float* __restrict__ bg,
                                                   unsigned short* __restrict__ qTp, unsigned short* __restrict__ kTp,
                                                   unsigned short* __restrict__ vTt, float* __restrict__ g){
  __shared__ short Al[64*8*8];
  __shared__ short Bl[64*8*8];
  int tid = threadIdx.x;
  int wave = tid >> 6, lane = tid & 63, l15 = lane & 15, sub = lane >> 4;
  int n0 = blockIdx.x*64, m0 = blockIdx.y*64;
  f32x4 acc[4];
  #pragma unroll
  for (int c = 0; c < 4; ++c) acc[c] = (f32x4){0.f,0.f,0.f,0.f};
  const s16x8* Ag = (const s16x8*)AB;
  const s16x8* Bg = (const s16x8*)wBt;
  s16x8* Al8 = (s16x8*)Al; s16x8* Bl8 = (s16x8*)Bl;
  for (int ks = 0; ks < 6; ++ks){
    int k0u = ks*8;
    #pragma unroll
    for (int j = 0; j < 2; ++j){
      int idx = tid*2 + j;
      int row = idx >> 3, u = idx & 7;
      Al8[row*8 + (u ^ (row & 7))] = Ag[(size_t)(m0 + row)*48 + k0u + u];
      Bl8[row*8 + (u ^ (row & 7))] = Bg[(size_t)(n0 + row)*48 + k0u + u];
    }
    __syncthreads();
    #pragma unroll
    for (int kk = 0; kk < 2; ++kk){
      int arow = wave*16 + l15;
      s16x8 af = Al8[arow*8 + ((kk*4 + sub) ^ (arow & 7))];
      #pragma unroll
      for (int c = 0; c < 4; ++c){
        int brow = c*16 + l15;
        s16x8 bf = Bl8[brow*8 + ((kk*4 + sub) ^ (brow & 7))];
        acc[c] = __builtin_amdgcn_mfma_f32_16x16x32_bf16(af, bf, acc[c], 0, 0, 0);
      }
    }
    __syncthreads();
  }
  int which = blockIdx.x / 6;
  int cb = n0 - which*384;
  if (which == 3){
    #pragma unroll
    for (int c = 0; c < 4; ++c){
      int col = cb + c*16 + l15;
      #pragma unroll
      for (int r = 0; r < 4; ++r){
        int row = m0 + wave*16 + sub*4 + r;
        float t = acc[c][r] + bg[col];
        g[(size_t)row*384 + col] = 1.f/(1.f + __expf(-t));
      }
    }
  } else if (which == 2){
    #pragma unroll
    for (int c = 0; c < 4; ++c){
      int col = cb + c*16 + l15;
      int h = col/24, d = col - h*24;
      unsigned p0 = pk_bf(acc[c][0], acc[c][1]);
      unsigned p1 = pk_bf(acc[c][2], acc[c][3]);
      size_t base = ((size_t)h*32 + d)*1024 + (size_t)(m0 + wave*16 + sub*4);
      *(uint2*)(vTt + base) = make_uint2(p0, p1);
    }
  } else {
    unsigned short* dst = which == 0 ? qTp : kTp;
    #pragma unroll
    for (int c = 0; c < 4; ++c){
      int col = cb + c*16 + l15;
      int h = col/24, d = col - h*24;
      #pragma unroll
      for (int r = 0; r < 4; ++r){
        int row = m0 + wave*16 + sub*4 + r;
        dst[((size_t)(h << 10) + row)*32 + d] = f2bf(acc[c][r]);
      }
    }
  }
}

// ---- z bias v5: 2-D tiles (4q x 16k); LDS-free staging; coalesced uint2 pbM stores ----
// tile = qt*4 rows x kt*16 cols; row r in tile -> pair (q0 + (r>>4))*1024 + k0 + (r&15)
__global__ __launch_bounds__(256) void zbias_kernel(const float* __restrict__ z, const unsigned short* __restrict__ wwB,
                                                    const float* __restrict__ TU, const float* __restrict__ mask,
                                                    unsigned short* __restrict__ pbM){
  __shared__ float sums[64];
  __shared__ float sqs[64];
  __shared__ float accT[64][17];
  int tid = threadIdx.x;
  int wave = tid >> 6, lane = tid & 63;
  int h = lane & 15, sub = lane >> 4;
  s16x8 bfr[4];
  #pragma unroll
  for (int kc = 0; kc < 4; ++kc)
    #pragma unroll
    for (int j = 0; j < 8; ++j) bfr[kc][j] = (short)wwB[(kc*32 + sub*8 + j)*16 + h];
  s16x8 ones1;
  #pragma unroll
  for (int j = 0; j < 8; ++j) ones1[j] = (h == 0) ? (short)0x3F80 : (short)0;
  int eh = tid >> 4, ej = tid & 15;      // epilogue: h, k-offset j
  float Te = TU[eh], Ue = TU[16 + eh];
  for (int it = 0; it < 4; ++it){
    int tile = blockIdx.x + it*4096;     // 16384 tiles
    int qt = tile >> 6, kt = tile & 63;
    int q0 = qt*4, k0 = kt*16;
    // this lane's A-fragment row: i = wave (q offset), j = h (k offset)
    const float* zrow = z + ((size_t)(q0 + wave)*1024 + k0 + h)*128;
    f32x4 acc  = {0.f, 0.f, 0.f, 0.f};
    f32x4 accS = {0.f, 0.f, 0.f, 0.f};
    f32x4 accG = {0.f, 0.f, 0.f, 0.f};
    #pragma unroll
    for (int kc = 0; kc < 4; ++kc){
      f32x4 v0 = *(const f32x4*)(zrow + kc*32 + sub*8);
      f32x4 v1 = *(const f32x4*)(zrow + kc*32 + sub*8 + 4);
      union { unsigned u[4]; s16x8 s; } cv;
      cv.u[0] = pk_bf(v0.x, v0.y); cv.u[1] = pk_bf(v0.z, v0.w);
      cv.u[2] = pk_bf(v1.x, v1.y); cv.u[3] = pk_bf(v1.z, v1.w);
      s16x8 af = cv.s;
      acc  = __builtin_amdgcn_mfma_f32_16x16x32_bf16(af, bfr[kc], acc, 0, 0, 0);
      accS = __builtin_amdgcn_mfma_f32_16x16x32_bf16(af, ones1, accS, 0, 0, 0);
      accG = __builtin_amdgcn_mfma_f32_16x16x32_bf16(af, af, accG, 0, 0, 0);
    }
    #pragma unroll
    for (int r = 0; r < 4; ++r) accT[wave*16 + sub*4 + r][h] = acc[r];
    if (h == 0){
      #pragma unroll
      for (int r = 0; r < 4; ++r) sums[wave*16 + sub*4 + r] = accS[r];
    }
    if (sub == (h >> 2)){
      int r = h & 3;
      float vq = r == 0 ? accG[0] : r == 1 ? accG[1] : r == 2 ? accG[2] : accG[3];
      sqs[wave*16 + h] = vq;
    }
    __syncthreads();
    // epilogue: thread (eh, ej) -> 4 q values (i=0..3) at k = k0+ej, h = eh
    int k = k0 + ej;
    float mb = 1e9f*(mask[k] - 1.f);
    unsigned short pv[4];
    #pragma unroll
    for (int i = 0; i < 4; ++i){
      int row = i*16 + ej;
      float mu = sums[row]*(1.f/128.f);
      float var = sqs[row]*(1.f/128.f) - mu*mu;
      float rs = rsqrtf(var + 1e-5f);
      pv[i] = f2bf(rs*(accT[row][eh] - mu*Te) + Ue + mb);
    }
    int qb = q0 >> 6, qg = (q0 >> 4) & 3, subq = (q0 >> 2) & 3;
    int kkt = k >> 6, c = (k >> 4) & 3, l15k = k & 15;
    size_t off = ((((size_t)(eh*16 + qb)*16 + kkt)*4 + qg)*4 + c)*256 + (size_t)(subq*16 + l15k)*4;
    *(uint2*)(pbM + off) = make_uint2(((unsigned)pv[1] << 16) | pv[0], ((unsigned)pv[3] << 16) | pv[2]);
    __syncthreads();
  }
}

// ---- attn v9: MFMA flash + K prefetch. block=(qb32,h) 512 blocks, 8 waves = 2 qg x 4 kkq ----
__global__ __launch_bounds__(512) void attn_kernel(const unsigned short* __restrict__ qTp, const unsigned short* __restrict__ kTp,
                                                   const unsigned short* __restrict__ vTt, const unsigned short* __restrict__ pbM,
                                                   const float* __restrict__ g, unsigned short* __restrict__ ogB){
  __shared__ float lds[8192];
  int tid = threadIdx.x;
  int wave = tid >> 6, lane = tid & 63, l15 = lane & 15, sub = lane >> 4;
  int qb32 = blockIdx.x, h = blockIdx.y;
  int qg_l = wave & 1, kkq = wave >> 1;
  int qrow = qb32*32 + qg_l*16 + l15;
  s16x8 qf = *(const s16x8*)(qTp + ((size_t)(h << 10) + qrow)*32 + sub*8);
  f32x4 o0 = {0.f,0.f,0.f,0.f}, o1 = {0.f,0.f,0.f,0.f};
  float m[4] = {-1e30f,-1e30f,-1e30f,-1e30f}, l[4] = {0.f,0.f,0.f,0.f};
  char* Pb = (char*)(lds + wave*1024);
  const unsigned short* kBase = kTp + ((size_t)(h << 10))*32;
  const unsigned short* vBase = vTt + (size_t)h*32*1024;
  int qb64 = qb32 >> 1, qg4 = (qb32 & 1)*2 + qg_l;
  const unsigned short* pbW = pbM + (size_t)(h*16 + qb64)*16*4096 + (size_t)qg4*1024 + (size_t)lane*4;
  s16x8 kfA0, kfA1, kfA2, kfA3;
  {
    int kk0 = (kkq*4)*64;
    kfA0 = *(const s16x8*)(kBase + (size_t)(kk0 +  0 + l15)*32 + sub*8);
    kfA1 = *(const s16x8*)(kBase + (size_t)(kk0 + 16 + l15)*32 + sub*8);
    kfA2 = *(const s16x8*)(kBase + (size_t)(kk0 + 32 + l15)*32 + sub*8);
    kfA3 = *(const s16x8*)(kBase + (size_t)(kk0 + 48 + l15)*32 + sub*8);
  }
  #pragma unroll
  for (int t = 0; t < 4; ++t){
    int kkt = kkq*4 + t;
    int kk0 = kkt*64;
    const unsigned short* pbt = pbW + (size_t)kkt*4096;
    uint2 pv0 = *(const uint2*)(pbt + 0);
    uint2 pv1 = *(const uint2*)(pbt + 256);
    uint2 pv2 = *(const uint2*)(pbt + 512);
    uint2 pv3 = *(const uint2*)(pbt + 768);
    f32x4 s[4];
    s[0] = __builtin_amdgcn_mfma_f32_16x16x32_bf16(qf, kfA0, (f32x4){0.f,0.f,0.f,0.f}, 0, 0, 0);
    s[1] = __builtin_amdgcn_mfma_f32_16x16x32_bf16(qf, kfA1, (f32x4){0.f,0.f,0.f,0.f}, 0, 0, 0);
    s[2] = __builtin_amdgcn_mfma_f32_16x16x32_bf16(qf, kfA2, (f32x4){0.f,0.f,0.f,0.f}, 0, 0, 0);
    s[3] = __builtin_amdgcn_mfma_f32_16x16x32_bf16(qf, kfA3, (f32x4){0.f,0.f,0.f,0.f}, 0, 0, 0);
    if (t < 3){                       // prefetch next K under softmax+PV
      int nk = kk0 + 64;
      kfA0 = *(const s16x8*)(kBase + (size_t)(nk +  0 + l15)*32 + sub*8);
      kfA1 = *(const s16x8*)(kBase + (size_t)(nk + 16 + l15)*32 + sub*8);
      kfA2 = *(const s16x8*)(kBase + (size_t)(nk + 32 + l15)*32 + sub*8);
      kfA3 = *(const s16x8*)(kBase + (size_t)(nk + 48 + l15)*32 + sub*8);
    }
    {
      uint2 pv[4] = {pv0, pv1, pv2, pv3};
      #pragma unroll
      for (int c = 0; c < 4; ++c){
        s[c][0] += bf2f((unsigned short)(pv[c].x & 0xffff));
        s[c][1] += bf2f((unsigned short)(pv[c].x >> 16));
        s[c][2] += bf2f((unsigned short)(pv[c].y & 0xffff));
        s[c][3] += bf2f((unsigned short)(pv[c].y >> 16));
      }
    }
    #pragma unroll
    for (int r = 0; r < 4; ++r){
      float pm = fmaxf(fmaxf(s[0][r], s[1][r]), fmaxf(s[2][r], s[3][r]));
      pm = fmaxf(pm, __shfl_xor(pm, 1));
      pm = fmaxf(pm, __shfl_xor(pm, 2));
      pm = fmaxf(pm, __shfl_xor(pm, 4));
      pm = fmaxf(pm, __shfl_xor(pm, 8));
      float mn = fmaxf(m[r], pm);
      float corr = __expf(m[r] - mn);
      m[r] = mn;
      float ps = 0.f;
      #pragma unroll
      for (int c = 0; c < 4; ++c){ s[c][r] = __expf(s[c][r] - mn); ps += s[c][r]; }
      ps += __shfl_xor(ps, 1); ps += __shfl_xor(ps, 2);
      ps += __shfl_xor(ps, 4); ps += __shfl_xor(ps, 8);
      l[r] = l[r]*corr + ps;
      o0[r] *= corr; o1[r] *= corr;
    }
    #pragma unroll
    for (int c = 0; c < 4; ++c){
      #pragma unroll
      for (int r = 0; r < 4; ++r){
        int qq = sub*4 + r;
        int byte = ((qq*128 + (c*16 + l15)*2)) ^ ((qq & 7) << 4);
        *(short*)(Pb + byte) = (short)f2bf(s[c][r]);
      }
    }
    #pragma unroll
    for (int kh = 0; kh < 2; ++kh){
      int byteA = (l15*128 + kh*64 + sub*16) ^ ((l15 & 7) << 4);
      s16x8 pa = *(const s16x8*)(Pb + byteA);
      s16x8 vb0 = *(const s16x8*)(vBase + (size_t)l15*1024 + kk0 + kh*32 + sub*8);
      s16x8 vb1 = *(const s16x8*)(vBase + (size_t)(16 + l15)*1024 + kk0 + kh*32 + sub*8);
      o0 = __builtin_amdgcn_mfma_f32_16x16x32_bf16(pa, vb0, o0, 0, 0, 0);
      o1 = __builtin_amdgcn_mfma_f32_16x16x32_bf16(pa, vb1, o1, 0, 0, 0);
    }
  }
  {
    float* cw = lds + wave*1024 + lane*16;
    cw[0] = o0[0]; cw[1] = o0[1]; cw[2] = o0[2]; cw[3] = o0[3];
    cw[4] = o1[0]; cw[5] = o1[1]; cw[6] = o1[2]; cw[7] = o1[3];
    cw[8] = m[0]; cw[9] = m[1]; cw[10] = m[2]; cw[11] = m[3];
    cw[12] = l[0]; cw[13] = l[1]; cw[14] = l[2]; cw[15] = l[3];
  }
  __syncthreads();
  if (kkq == 0){
    #pragma unroll
    for (int k2 = 1; k2 < 4; ++k2){
      const float* c2 = lds + (size_t)(k2*2 + qg_l)*1024 + lane*16;
      #pragma unroll
      for (int r = 0; r < 4; ++r){
        float m2 = c2[8 + r], l2 = c2[12 + r];
        float nm = fmaxf(m[r], m2);
        float f1 = __expf(m[r] - nm), f2 = __expf(m2 - nm);
        l[r] = l[r]*f1 + l2*f2;
        o0[r] = o0[r]*f1 + c2[r]*f2;
        o1[r] = o1[r]*f1 + c2[4 + r]*f2;
        m[r] = nm;
      }
    }
    #pragma unroll
    for (int r = 0; r < 4; ++r){
      float inv = 1.f/l[r];
      int q = qb32*32 + qg_l*16 + sub*4 + r;
      size_t base = (size_t)q*384 + h*24;
      ogB[base + l15] = f2bf(g[base + l15]*o0[r]*inv);
      if (l15 < 8) ogB[base + 16 + l15] = f2bf(g[base + 16 + l15]*o1[r]*inv);
    }
  }
}

// ---- final projection: ogB[1024x384]bf16 @ wo^T bf16 via MFMA, + bo ----
__global__ __launch_bounds__(256) void gemm_out(const unsigned short* __restrict__ AB,
                                                const unsigned short* __restrict__ wBo,
                                                const float* __restrict__ bo, float* __restrict__ dst){
  __shared__ short Al[64*8*8];
  __shared__ short Bl[64*8*8];
  int tid = threadIdx.x;
  int wave = tid >> 6, lane = tid & 63, l15 = lane & 15, sub = lane >> 4;
  int n0 = blockIdx.x*64, m0 = blockIdx.y*64;
  f32x4 acc[4];
  #pragma unroll
  for (int c = 0; c < 4; ++c) acc[c] = (f32x4){0.f,0.f,0.f,0.f};
  const s16x8* Ag = (const s16x8*)AB;
  const s16x8* Bg = (const s16x8*)wBo;
  s16x8* Al8 = (s16x8*)Al; s16x8* Bl8 = (s16x8*)Bl;
  for (int ks = 0; ks < 6; ++ks){
    int k0u = ks*8;
    #pragma unroll
    for (int j = 0; j < 2; ++j){
      int idx = tid*2 + j;
      int row = idx >> 3, u = idx & 7;
      Al8[row*8 + (u ^ (row & 7))] = Ag[(size_t)(m0 + row)*48 + k0u + u];
      Bl8[row*8 + (u ^ (row & 7))] = Bg[(size_t)(n0 + row)*48 + k0u + u];
    }
    __syncthreads();
    #pragma unroll
    for (int kk = 0; kk < 2; ++kk){
      int arow = wave*16 + l15;
      s16x8 af = Al8[arow*8 + ((kk*4 + sub) ^ (arow & 7))];
      #pragma unroll
      for (int c = 0; c < 4; ++c){
        int brow = c*16 + l15;
        s16x8 bf = Bl8[brow*8 + ((kk*4 + sub) ^ (brow & 7))];
        acc[c] = __builtin_amdgcn_mfma_f32_16x16x32_bf16(af, bf, acc[c], 0, 0, 0);
      }
    }
    __syncthreads();
  }
  #pragma unroll
  for (int c = 0; c < 4; ++c){
    int col = n0 + c*16 + l15;
    float b = bo[col];
    #pragma unroll
    for (int r = 0; r < 4; ++r){
      int row = m0 + wave*16 + sub*4 + r;
      dst[(size_t)row*384 + col] = acc[c][r] + b;
    }
  }
}

extern "C" void kernel_launch(void* const* d_in, const int* in_sizes, int n_in,
                              void* d_out, int out_size, void* d_ws, size_t ws_size,
                              hipStream_t stream){
  const float* a      = (const float*)d_in[0];
  const float* z      = (const float*)d_in[1];
  const float* mask   = (const float*)d_in[2];
  const float* ln_a_w = (const float*)d_in[3];
  const float* ln_a_b = (const float*)d_in[4];
  const float* ln_z_w = (const float*)d_in[5];
  const float* ln_z_b = (const float*)d_in[6];
  const float* w_z    = (const float*)d_in[7];
  const float* wq     = (const float*)d_in[8];
  const float* wk     = (const float*)d_in[9];
  const float* wv     = (const float*)d_in[10];
  const float* wg     = (const float*)d_in[11];
  const float* bg     = (const float*)d_in[12];
  const float* wo     = (const float*)d_in[13];
  const float* bo     = (const float*)d_in[14];

  char* ws = (char*)d_ws;
  unsigned short* a_lnB = (unsigned short*)(ws + ((size_t)0u));
  unsigned short* wBall = (unsigned short*)(ws + ((size_t)1u << 20));
  unsigned short* qTp   = (unsigned short*)(ws + ((size_t)4u << 20));
  unsigned short* kTp   = (unsigned short*)(ws + ((size_t)6u << 20));
  unsigned short* vTt   = (unsigned short*)(ws + ((size_t)8u << 20));
  float* g    = (float*)(ws + ((size_t)10u << 20));
  unsigned short* ogB = (unsigned short*)(ws + ((size_t)12u << 20));
  unsigned short* wwB = (unsigned short*)(ws + ((size_t)14u << 20));
  float* TU   = (float*)(ws + ((size_t)14u << 20) + 8192);
  unsigned short* pbM = (unsigned short*)(ws + ((size_t)24u << 20));

  hipLaunchKernelGGL(prep_kernel, dim3(629), dim3(256), 0, stream, a, ln_a_w, ln_a_b,
                     ln_z_w, ln_z_b, w_z, wq, wk, wv, wg, wo, a_lnB, wBall, wwB, TU, qTp, kTp, vTt);
  hipLaunchKernelGGL(qkvg_kernel, dim3(24,16), dim3(256), 0, stream, a_lnB, wBall, bg, qTp, kTp, vTt, g);
  hipLaunchKernelGGL(zbias_kernel, dim3(4096), dim3(256), 0, stream, z, wwB, TU, mask, pbM);
  hipLaunchKernelGGL(attn_kernel, dim3(32,16), dim3(512), 0, stream, qTp, kTp, vTt, pbM, g, ogB);
  hipLaunchKernelGGL(gemm_out, dim3(6,16), dim3(256), 0, stream, ogB, wBall + (size_t)4*384*384, bo, (float*)d_out);
}

// Round 15
// 158.992 us; speedup vs baseline: 7.7413x; 1.0156x over previous
//
#include <hip/hip_runtime.h>
#include <hip/hip_bf16.h>

typedef float f32x4 __attribute__((ext_vector_type(4)));
typedef short s16x8 __attribute__((ext_vector_type(8)));

__device__ __forceinline__ unsigned short f2bf(float x){
  unsigned u = __float_as_uint(x);
  u += 0x7fffu + ((u >> 16) & 1u);
  return (unsigned short)(u >> 16);
}
__device__ __forceinline__ float bf2f(unsigned short h){
  return __uint_as_float(((unsigned)h) << 16);
}
__device__ __forceinline__ unsigned pk_bf(float a, float b){
  __hip_bfloat162 t = __float22bfloat162_rn(make_float2(a, b));
  return *reinterpret_cast<unsigned*>(&t);
}

// ---- prep: weight transpose->bf16 (0..179), ln_a (180..435), setup (436), zero-pads (437..628) ----
__global__ __launch_bounds__(256) void prep_kernel(const float* __restrict__ a, const float* __restrict__ ln_a_w,
                             const float* __restrict__ ln_a_b, const float* __restrict__ lnzw,
                             const float* __restrict__ lnzb, const float* __restrict__ w_z,
                             const float* __restrict__ wq, const float* __restrict__ wk,
                             const float* __restrict__ wv, const float* __restrict__ wg,
                             const float* __restrict__ wo,
                             unsigned short* __restrict__ a_lnB, unsigned short* __restrict__ wBall,
                             unsigned short* __restrict__ wwB, float* __restrict__ TU,
                             unsigned short* __restrict__ qTp, unsigned short* __restrict__ kTp,
                             unsigned short* __restrict__ vTt){
  int bid = blockIdx.x, tid = threadIdx.x;
  if (bid < 180){
    __shared__ float t[64][65];
    int mat = bid/36, tt = bid - mat*36;
    int c0 = (tt % 6)*64, k0 = (tt / 6)*64;
    const float* src = mat == 0 ? wq : mat == 1 ? wk : mat == 2 ? wv : mat == 3 ? wg : wo;
    int r = tid >> 4, c4 = (tid & 15)*4;
    #pragma unroll
    for (int rr = 0; rr < 4; ++rr){
      float4 v = *(const float4*)(src + (size_t)(k0 + r + rr*16)*384 + c0 + c4);
      t[r + rr*16][c4+0] = v.x; t[r + rr*16][c4+1] = v.y;
      t[r + rr*16][c4+2] = v.z; t[r + rr*16][c4+3] = v.w;
    }
    __syncthreads();
    float scale = (mat == 0) ? 0.20412414523193154f : 1.f;
    int cc = tid >> 2, kp = (tid & 3)*16;
    unsigned ow[8];
    #pragma unroll
    for (int j = 0; j < 8; ++j)
      ow[j] = pk_bf(t[kp + 2*j][cc]*scale, t[kp + 2*j + 1][cc]*scale);
    unsigned short* dst = wBall + ((size_t)(mat*384 + c0 + cc)*384 + k0 + kp);
    *(uint4*)dst       = make_uint4(ow[0], ow[1], ow[2], ow[3]);
    *(uint4*)(dst + 8) = make_uint4(ow[4], ow[5], ow[6], ow[7]);
  } else if (bid < 436){
    int r = (bid - 180)*4 + (tid >> 6), l = tid & 63;
    const float* ap = a + (size_t)r*384;
    float x[6]; float s = 0.f, sq = 0.f;
    #pragma unroll
    for (int i = 0; i < 6; ++i){ x[i] = ap[i*64 + l]; s += x[i]; sq += x[i]*x[i]; }
    #pragma unroll
    for (int off = 32; off; off >>= 1){ s += __shfl_xor(s, off); sq += __shfl_xor(sq, off); }
    float mu = s*(1.f/384.f);
    float var = sq*(1.f/384.f) - mu*mu;
    float rs = rsqrtf(var + 1e-5f);
    #pragma unroll
    for (int i = 0; i < 6; ++i){ int c = i*64 + l; a_lnB[(size_t)r*384 + c] = f2bf((x[i]-mu)*rs*ln_a_w[c] + ln_a_b[c]); }
  } else if (bid == 436){
    if (tid < 128){
      float lw = lnzw[tid];
      #pragma unroll
      for (int h = 0; h < 16; ++h) wwB[tid*16 + h] = f2bf(lw * w_z[tid*16 + h]);
    }
    if (tid < 16){
      float T = 0.f, U = 0.f;
      for (int c = 0; c < 128; ++c){ T += lnzw[c]*w_z[c*16 + tid]; U += lnzb[c]*w_z[c*16 + tid]; }
      TU[tid] = T; TU[16 + tid] = U;
    }
  } else {
    int t = (bid - 437)*256 + tid;       // 0..49151
    uint4 zv = make_uint4(0,0,0,0);
    if (t < 16384)      *(uint4*)(qTp + (size_t)t*32 + 24) = zv;
    else if (t < 32768) *(uint4*)(kTp + (size_t)(t - 16384)*32 + 24) = zv;
    else {
      int t2 = t - 32768;                 // 0..16383
      int h = t2 >> 10, w = t2 & 1023;
      *(uint4*)(vTt + ((size_t)h*32 + 24)*1024 + (size_t)w*8) = zv;
    }
  }
}

// ---- fused QKVG MFMA: emits qTp/kTp bf16 [h][1024][32], vTt bf16 [h][32][1024], g f32 ----
__global__ __launch_bounds__(256) void qkvg_kernel(const unsigned short* __restrict__ AB,
                                                   const unsigned short* __restrict__ wBt,
                                                   const float* __restrict__ bg,
                                                   unsigned short* __restrict__ qTp, unsigned short* __restrict__ kTp,
                                                   unsigned short* __restrict__ vTt, float* __restrict__ g){
  __shared__ short Al[64*8*8];
  __shared__ short Bl[64*8*8];
  int tid = threadIdx.x;
  int wave = tid >> 6, lane = tid & 63, l15 = lane & 15, sub = lane >> 4;
  int n0 = blockIdx.x*64, m0 = blockIdx.y*64;
  f32x4 acc[4];
  #pragma unroll
  for (int c = 0; c < 4; ++c) acc[c] = (f32x4){0.f,0.f,0.f,0.f};
  const s16x8* Ag = (const s16x8*)AB;
  const s16x8* Bg = (const s16x8*)wBt;
  s16x8* Al8 = (s16x8*)Al; s16x8* Bl8 = (s16x8*)Bl;
  for (int ks = 0; ks < 6; ++ks){
    int k0u = ks*8;
    #pragma unroll
    for (int j = 0; j < 2; ++j){
      int idx = tid*2 + j;
      int row = idx >> 3, u = idx & 7;
      Al8[row*8 + (u ^ (row & 7))] = Ag[(size_t)(m0 + row)*48 + k0u + u];
      Bl8[row*8 + (u ^ (row & 7))] = Bg[(size_t)(n0 + row)*48 + k0u + u];
    }
    __syncthreads();
    #pragma unroll
    for (int kk = 0; kk < 2; ++kk){
      int arow = wave*16 + l15;
      s16x8 af = Al8[arow*8 + ((kk*4 + sub) ^ (arow & 7))];
      #pragma unroll
      for (int c = 0; c < 4; ++c){
        int brow = c*16 + l15;
        s16x8 bf = Bl8[brow*8 + ((kk*4 + sub) ^ (brow & 7))];
        acc[c] = __builtin_amdgcn_mfma_f32_16x16x32_bf16(af, bf, acc[c], 0, 0, 0);
      }
    }
    __syncthreads();
  }
  int which = blockIdx.x / 6;
  int cb = n0 - which*384;
  if (which == 3){
    #pragma unroll
    for (int c = 0; c < 4; ++c){
      int col = cb + c*16 + l15;
      #pragma unroll
      for (int r = 0; r < 4; ++r){
        int row = m0 + wave*16 + sub*4 + r;
        float t = acc[c][r] + bg[col];
        g[(size_t)row*384 + col] = 1.f/(1.f + __expf(-t));
      }
    }
  } else if (which == 2){
    #pragma unroll
    for (int c = 0; c < 4; ++c){
      int col = cb + c*16 + l15;
      int h = col/24, d = col - h*24;
      unsigned p0 = pk_bf(acc[c][0], acc[c][1]);
      unsigned p1 = pk_bf(acc[c][2], acc[c][3]);
      size_t base = ((size_t)h*32 + d)*1024 + (size_t)(m0 + wave*16 + sub*4);
      *(uint2*)(vTt + base) = make_uint2(p0, p1);
    }
  } else {
    unsigned short* dst = which == 0 ? qTp : kTp;
    #pragma unroll
    for (int c = 0; c < 4; ++c){
      int col = cb + c*16 + l15;
      int h = col/24, d = col - h*24;
      #pragma unroll
      for (int r = 0; r < 4; ++r){
        int row = m0 + wave*16 + sub*4 + r;
        dst[((size_t)(h << 10) + row)*32 + d] = f2bf(acc[c][r]);
      }
    }
  }
}

// ---- z bias v6: 2-D tiles (4q x 16k); LDS-free staging; double-buffered LDS state; coalesced stores ----
__global__ __launch_bounds__(256) void zbias_kernel(const float* __restrict__ z, const unsigned short* __restrict__ wwB,
                                                    const float* __restrict__ TU, const float* __restrict__ mask,
                                                    unsigned short* __restrict__ pbM){
  __shared__ float sums[2][64];
  __shared__ float sqs[2][64];
  __shared__ float accT[2][64][17];
  int tid = threadIdx.x;
  int wave = tid >> 6, lane = tid & 63;
  int h = lane & 15, sub = lane >> 4;
  s16x8 bfr[4];
  #pragma unroll
  for (int kc = 0; kc < 4; ++kc)
    #pragma unroll
    for (int j = 0; j < 8; ++j) bfr[kc][j] = (short)wwB[(kc*32 + sub*8 + j)*16 + h];
  s16x8 ones1;
  #pragma unroll
  for (int j = 0; j < 8; ++j) ones1[j] = (h == 0) ? (short)0x3F80 : (short)0;
  int eh = tid >> 4, ej = tid & 15;
  float Te = TU[eh], Ue = TU[16 + eh];
  for (int it = 0; it < 4; ++it){
    int bb = it & 1;
    int tile = blockIdx.x + it*4096;
    int qt = tile >> 6, kt = tile & 63;
    int q0 = qt*4, k0 = kt*16;
    const float* zrow = z + ((size_t)(q0 + wave)*1024 + k0 + h)*128;
    f32x4 acc  = {0.f, 0.f, 0.f, 0.f};
    f32x4 accS = {0.f, 0.f, 0.f, 0.f};
    f32x4 accG = {0.f, 0.f, 0.f, 0.f};
    #pragma unroll
    for (int kc = 0; kc < 4; ++kc){
      f32x4 v0 = *(const f32x4*)(zrow + kc*32 + sub*8);
      f32x4 v1 = *(const f32x4*)(zrow + kc*32 + sub*8 + 4);
      union { unsigned u[4]; s16x8 s; } cv;
      cv.u[0] = pk_bf(v0.x, v0.y); cv.u[1] = pk_bf(v0.z, v0.w);
      cv.u[2] = pk_bf(v1.x, v1.y); cv.u[3] = pk_bf(v1.z, v1.w);
      s16x8 af = cv.s;
      acc  = __builtin_amdgcn_mfma_f32_16x16x32_bf16(af, bfr[kc], acc, 0, 0, 0);
      accS = __builtin_amdgcn_mfma_f32_16x16x32_bf16(af, ones1, accS, 0, 0, 0);
      accG = __builtin_amdgcn_mfma_f32_16x16x32_bf16(af, af, accG, 0, 0, 0);
    }
    #pragma unroll
    for (int r = 0; r < 4; ++r) accT[bb][wave*16 + sub*4 + r][h] = acc[r];
    if (h == 0){
      #pragma unroll
      for (int r = 0; r < 4; ++r) sums[bb][wave*16 + sub*4 + r] = accS[r];
    }
    if (sub == (h >> 2)){
      int r = h & 3;
      float vq = r == 0 ? accG[0] : r == 1 ? accG[1] : r == 2 ? accG[2] : accG[3];
      sqs[bb][wave*16 + h] = vq;
    }
    __syncthreads();
    int k = k0 + ej;
    float mb = 1e9f*(mask[k] - 1.f);
    unsigned short pv[4];
    #pragma unroll
    for (int i = 0; i < 4; ++i){
      int row = i*16 + ej;
      float mu = sums[bb][row]*(1.f/128.f);
      float var = sqs[bb][row]*(1.f/128.f) - mu*mu;
      float rs = rsqrtf(var + 1e-5f);
      pv[i] = f2bf(rs*(accT[bb][row][eh] - mu*Te) + Ue + mb);
    }
    int qb = q0 >> 6, qg = (q0 >> 4) & 3, subq = (q0 >> 2) & 3;
    int kkt = k >> 6, c = (k >> 4) & 3, l15k = k & 15;
    size_t off = ((((size_t)(eh*16 + qb)*16 + kkt)*4 + qg)*4 + c)*256 + (size_t)(subq*16 + l15k)*4;
    *(uint2*)(pbM + off) = make_uint2(((unsigned)pv[1] << 16) | pv[0], ((unsigned)pv[3] << 16) | pv[2]);
  }
}

// ---- attn v10: MFMA flash; ALL pb prefetched to regs; K double-buffer prefetch ----
__global__ __launch_bounds__(512) void attn_kernel(const unsigned short* __restrict__ qTp, const unsigned short* __restrict__ kTp,
                                                   const unsigned short* __restrict__ vTt, const unsigned short* __restrict__ pbM,
                                                   const float* __restrict__ g, unsigned short* __restrict__ ogB){
  __shared__ float lds[8192];
  int tid = threadIdx.x;
  int wave = tid >> 6, lane = tid & 63, l15 = lane & 15, sub = lane >> 4;
  int qb32 = blockIdx.x, h = blockIdx.y;
  int qg_l = wave & 1, kkq = wave >> 1;
  int qrow = qb32*32 + qg_l*16 + l15;
  int qb64 = qb32 >> 1, qg4 = (qb32 & 1)*2 + qg_l;
  const unsigned short* kBase = kTp + ((size_t)(h << 10))*32;
  const unsigned short* vBase = vTt + (size_t)h*32*1024;
  const unsigned short* pbW = pbM + (size_t)(h*16 + qb64)*16*4096 + (size_t)qg4*1024 + (size_t)lane*4;
  // prefetch ALL pb tiles (16 x uint2) — latency hides under q/K loads + first MFMAs
  uint2 pvAll[4][4];
  #pragma unroll
  for (int t = 0; t < 4; ++t){
    const unsigned short* pbt = pbW + (size_t)(kkq*4 + t)*4096;
    pvAll[t][0] = *(const uint2*)(pbt + 0);
    pvAll[t][1] = *(const uint2*)(pbt + 256);
    pvAll[t][2] = *(const uint2*)(pbt + 512);
    pvAll[t][3] = *(const uint2*)(pbt + 768);
  }
  s16x8 qf = *(const s16x8*)(qTp + ((size_t)(h << 10) + qrow)*32 + sub*8);
  f32x4 o0 = {0.f,0.f,0.f,0.f}, o1 = {0.f,0.f,0.f,0.f};
  float m[4] = {-1e30f,-1e30f,-1e30f,-1e30f}, l[4] = {0.f,0.f,0.f,0.f};
  char* Pb = (char*)(lds + wave*1024);
  s16x8 kfA0, kfA1, kfA2, kfA3;
  {
    int kk0 = (kkq*4)*64;
    kfA0 = *(const s16x8*)(kBase + (size_t)(kk0 +  0 + l15)*32 + sub*8);
    kfA1 = *(const s16x8*)(kBase + (size_t)(kk0 + 16 + l15)*32 + sub*8);
    kfA2 = *(const s16x8*)(kBase + (size_t)(kk0 + 32 + l15)*32 + sub*8);
    kfA3 = *(const s16x8*)(kBase + (size_t)(kk0 + 48 + l15)*32 + sub*8);
  }
  #pragma unroll
  for (int t = 0; t < 4; ++t){
    int kkt = kkq*4 + t;
    int kk0 = kkt*64;
    f32x4 s[4];
    s[0] = __builtin_amdgcn_mfma_f32_16x16x32_bf16(qf, kfA0, (f32x4){0.f,0.f,0.f,0.f}, 0, 0, 0);
    s[1] = __builtin_amdgcn_mfma_f32_16x16x32_bf16(qf, kfA1, (f32x4){0.f,0.f,0.f,0.f}, 0, 0, 0);
    s[2] = __builtin_amdgcn_mfma_f32_16x16x32_bf16(qf, kfA2, (f32x4){0.f,0.f,0.f,0.f}, 0, 0, 0);
    s[3] = __builtin_amdgcn_mfma_f32_16x16x32_bf16(qf, kfA3, (f32x4){0.f,0.f,0.f,0.f}, 0, 0, 0);
    if (t < 3){
      int nk = kk0 + 64;
      kfA0 = *(const s16x8*)(kBase + (size_t)(nk +  0 + l15)*32 + sub*8);
      kfA1 = *(const s16x8*)(kBase + (size_t)(nk + 16 + l15)*32 + sub*8);
      kfA2 = *(const s16x8*)(kBase + (size_t)(nk + 32 + l15)*32 + sub*8);
      kfA3 = *(const s16x8*)(kBase + (size_t)(nk + 48 + l15)*32 + sub*8);
    }
    #pragma unroll
    for (int c = 0; c < 4; ++c){
      s[c][0] += bf2f((unsigned short)(pvAll[t][c].x & 0xffff));
      s[c][1] += bf2f((unsigned short)(pvAll[t][c].x >> 16));
      s[c][2] += bf2f((unsigned short)(pvAll[t][c].y & 0xffff));
      s[c][3] += bf2f((unsigned short)(pvAll[t][c].y >> 16));
    }
    #pragma unroll
    for (int r = 0; r < 4; ++r){
      float pm = fmaxf(fmaxf(s[0][r], s[1][r]), fmaxf(s[2][r], s[3][r]));
      pm = fmaxf(pm, __shfl_xor(pm, 1));
      pm = fmaxf(pm, __shfl_xor(pm, 2));
      pm = fmaxf(pm, __shfl_xor(pm, 4));
      pm = fmaxf(pm, __shfl_xor(pm, 8));
      float mn = fmaxf(m[r], pm);
      float corr = __expf(m[r] - mn);
      m[r] = mn;
      float ps = 0.f;
      #pragma unroll
      for (int c = 0; c < 4; ++c){ s[c][r] = __expf(s[c][r] - mn); ps += s[c][r]; }
      ps += __shfl_xor(ps, 1); ps += __shfl_xor(ps, 2);
      ps += __shfl_xor(ps, 4); ps += __shfl_xor(ps, 8);
      l[r] = l[r]*corr + ps;
      o0[r] *= corr; o1[r] *= corr;
    }
    #pragma unroll
    for (int c = 0; c < 4; ++c){
      #pragma unroll
      for (int r = 0; r < 4; ++r){
        int qq = sub*4 + r;
        int byte = ((qq*128 + (c*16 + l15)*2)) ^ ((qq & 7) << 4);
        *(short*)(Pb + byte) = (short)f2bf(s[c][r]);
      }
    }
    #pragma unroll
    for (int kh = 0; kh < 2; ++kh){
      int byteA = (l15*128 + kh*64 + sub*16) ^ ((l15 & 7) << 4);
      s16x8 pa = *(const s16x8*)(Pb + byteA);
      s16x8 vb0 = *(const s16x8*)(vBase + (size_t)l15*1024 + kk0 + kh*32 + sub*8);
      s16x8 vb1 = *(const s16x8*)(vBase + (size_t)(16 + l15)*1024 + kk0 + kh*32 + sub*8);
      o0 = __builtin_amdgcn_mfma_f32_16x16x32_bf16(pa, vb0, o0, 0, 0, 0);
      o1 = __builtin_amdgcn_mfma_f32_16x16x32_bf16(pa, vb1, o1, 0, 0, 0);
    }
  }
  {
    float* cw = lds + wave*1024 + lane*16;
    cw[0] = o0[0]; cw[1] = o0[1]; cw[2] = o0[2]; cw[3] = o0[3];
    cw[4] = o1[0]; cw[5] = o1[1]; cw[6] = o1[2]; cw[7] = o1[3];
    cw[8] = m[0]; cw[9] = m[1]; cw[10] = m[2]; cw[11] = m[3];
    cw[12] = l[0]; cw[13] = l[1]; cw[14] = l[2]; cw[15] = l[3];
  }
  __syncthreads();
  if (kkq == 0){
    #pragma unroll
    for (int k2 = 1; k2 < 4; ++k2){
      const float* c2 = lds + (size_t)(k2*2 + qg_l)*1024 + lane*16;
      #pragma unroll
      for (int r = 0; r < 4; ++r){
        float m2 = c2[8 + r], l2 = c2[12 + r];
        float nm = fmaxf(m[r], m2);
        float f1 = __expf(m[r] - nm), f2 = __expf(m2 - nm);
        l[r] = l[r]*f1 + l2*f2;
        o0[r] = o0[r]*f1 + c2[r]*f2;
        o1[r] = o1[r]*f1 + c2[4 + r]*f2;
        m[r] = nm;
      }
    }
    #pragma unroll
    for (int r = 0; r < 4; ++r){
      float inv = 1.f/l[r];
      int q = qb32*32 + qg_l*16 + sub*4 + r;
      size_t base = (size_t)q*384 + h*24;
      ogB[base + l15] = f2bf(g[base + l15]*o0[r]*inv);
      if (l15 < 8) ogB[base + 16 + l15] = f2bf(g[base + 16 + l15]*o1[r]*inv);
    }
  }
}

// ---- final projection: ogB[1024x384]bf16 @ wo^T bf16 via MFMA, + bo ----
__global__ __launch_bounds__(256) void gemm_out(const unsigned short* __restrict__ AB,
                                                const unsigned short* __restrict__ wBo,
                                                const float* __restrict__ bo, float* __restrict__ dst){
  __shared__ short Al[64*8*8];
  __shared__ short Bl[64*8*8];
  int tid = threadIdx.x;
  int wave = tid >> 6, lane = tid & 63, l15 = lane & 15, sub = lane >> 4;
  int n0 = blockIdx.x*64, m0 = blockIdx.y*64;
  f32x4 acc[4];
  #pragma unroll
  for (int c = 0; c < 4; ++c) acc[c] = (f32x4){0.f,0.f,0.f,0.f};
  const s16x8* Ag = (const s16x8*)AB;
  const s16x8* Bg = (const s16x8*)wBo;
  s16x8* Al8 = (s16x8*)Al; s16x8* Bl8 = (s16x8*)Bl;
  for (int ks = 0; ks < 6; ++ks){
    int k0u = ks*8;
    #pragma unroll
    for (int j = 0; j < 2; ++j){
      int idx = tid*2 + j;
      int row = idx >> 3, u = idx & 7;
      Al8[row*8 + (u ^ (row & 7))] = Ag[(size_t)(m0 + row)*48 + k0u + u];
      Bl8[row*8 + (u ^ (row & 7))] = Bg[(size_t)(n0 + row)*48 + k0u + u];
    }
    __syncthreads();
    #pragma unroll
    for (int kk = 0; kk < 2; ++kk){
      int arow = wave*16 + l15;
      s16x8 af = Al8[arow*8 + ((kk*4 + sub) ^ (arow & 7))];
      #pragma unroll
      for (int c = 0; c < 4; ++c){
        int brow = c*16 + l15;
        s16x8 bf = Bl8[brow*8 + ((kk*4 + sub) ^ (brow & 7))];
        acc[c] = __builtin_amdgcn_mfma_f32_16x16x32_bf16(af, bf, acc[c], 0, 0, 0);
      }
    }
    __syncthreads();
  }
  #pragma unroll
  for (int c = 0; c < 4; ++c){
    int col = n0 + c*16 + l15;
    float b = bo[col];
    #pragma unroll
    for (int r = 0; r < 4; ++r){
      int row = m0 + wave*16 + sub*4 + r;
      dst[(size_t)row*384 + col] = acc[c][r] + b;
    }
  }
}

extern "C" void kernel_launch(void* const* d_in, const int* in_sizes, int n_in,
                              void* d_out, int out_size, void* d_ws, size_t ws_size,
                              hipStream_t stream){
  const float* a      = (const float*)d_in[0];
  const float* z      = (const float*)d_in[1];
  const float* mask   = (const float*)d_in[2];
  const float* ln_a_w = (const float*)d_in[3];
  const float* ln_a_b = (const float*)d_in[4];
  const float* ln_z_w = (const float*)d_in[5];
  const float* ln_z_b = (const float*)d_in[6];
  const float* w_z    = (const float*)d_in[7];
  const float* wq     = (const float*)d_in[8];
  const float* wk     = (const float*)d_in[9];
  const float* wv     = (const float*)d_in[10];
  const float* wg     = (const float*)d_in[11];
  const float* bg     = (const float*)d_in[12];
  const float* wo     = (const float*)d_in[13];
  const float* bo     = (const float*)d_in[14];

  char* ws = (char*)d_ws;
  unsigned short* a_lnB = (unsigned short*)(ws + ((size_t)0u));
  unsigned short* wBall = (unsigned short*)(ws + ((size_t)1u << 20));
  unsigned short* qTp   = (unsigned short*)(ws + ((size_t)4u << 20));
  unsigned short* kTp   = (unsigned short*)(ws + ((size_t)6u << 20));
  unsigned short* vTt   = (unsigned short*)(ws + ((size_t)8u << 20));
  float* g    = (float*)(ws + ((size_t)10u << 20));
  unsigned short* ogB = (unsigned short*)(ws + ((size_t)12u << 20));
  unsigned short* wwB = (unsigned short*)(ws + ((size_t)14u << 20));
  float* TU   = (float*)(ws + ((size_t)14u << 20) + 8192);
  unsigned short* pbM = (unsigned short*)(ws + ((size_t)24u << 20));

  hipLaunchKernelGGL(prep_kernel, dim3(629), dim3(256), 0, stream, a, ln_a_w, ln_a_b,
                     ln_z_w, ln_z_b, w_z, wq, wk, wv, wg, wo, a_lnB, wBall, wwB, TU, qTp, kTp, vTt);
  hipLaunchKernelGGL(qkvg_kernel, dim3(24,16), dim3(256), 0, stream, a_lnB, wBall, bg, qTp, kTp, vTt, g);
  hipLaunchKernelGGL(zbias_kernel, dim3(4096), dim3(256), 0, stream, z, wwB, TU, mask, pbM);
  hipLaunchKernelGGL(attn_kernel, dim3(32,16), dim3(512), 0, stream, qTp, kTp, vTt, pbM, g, ogB);
  hipLaunchKernelGGL(gemm_out, dim3(6,16), dim3(256), 0, stream, ogB, wBall + (size_t)4*384*384, bo, (float*)d_out);
}

// Round 16
// 156.784 us; speedup vs baseline: 7.8504x; 1.0141x over previous
//
#include <hip/hip_runtime.h>
#include <hip/hip_bf16.h>

typedef float f32x4 __attribute__((ext_vector_type(4)));
typedef short s16x8 __attribute__((ext_vector_type(8)));

__device__ __forceinline__ unsigned short f2bf(float x){
  unsigned u = __float_as_uint(x);
  u += 0x7fffu + ((u >> 16) & 1u);
  return (unsigned short)(u >> 16);
}
__device__ __forceinline__ float bf2f(unsigned short h){
  return __uint_as_float(((unsigned)h) << 16);
}
__device__ __forceinline__ unsigned pk_bf(float a, float b){
  __hip_bfloat162 t = __float22bfloat162_rn(make_float2(a, b));
  return *reinterpret_cast<unsigned*>(&t);
}

// ---- prep: weight transpose->bf16 (0..179), ln_a (180..435), setup (436), zero-pads (437..628) ----
__global__ __launch_bounds__(256) void prep_kernel(const float* __restrict__ a, const float* __restrict__ ln_a_w,
                             const float* __restrict__ ln_a_b, const float* __restrict__ lnzw,
                             const float* __restrict__ lnzb, const float* __restrict__ w_z,
                             const float* __restrict__ wq, const float* __restrict__ wk,
                             const float* __restrict__ wv, const float* __restrict__ wg,
                             const float* __restrict__ wo,
                             unsigned short* __restrict__ a_lnB, unsigned short* __restrict__ wBall,
                             unsigned short* __restrict__ wwB, float* __restrict__ TU,
                             unsigned short* __restrict__ qTp, unsigned short* __restrict__ kTp,
                             unsigned short* __restrict__ vTt){
  int bid = blockIdx.x, tid = threadIdx.x;
  if (bid < 180){
    __shared__ float t[64][65];
    int mat = bid/36, tt = bid - mat*36;
    int c0 = (tt % 6)*64, k0 = (tt / 6)*64;
    const float* src = mat == 0 ? wq : mat == 1 ? wk : mat == 2 ? wv : mat == 3 ? wg : wo;
    int r = tid >> 4, c4 = (tid & 15)*4;
    #pragma unroll
    for (int rr = 0; rr < 4; ++rr){
      float4 v = *(const float4*)(src + (size_t)(k0 + r + rr*16)*384 + c0 + c4);
      t[r + rr*16][c4+0] = v.x; t[r + rr*16][c4+1] = v.y;
      t[r + rr*16][c4+2] = v.z; t[r + rr*16][c4+3] = v.w;
    }
    __syncthreads();
    float scale = (mat == 0) ? 0.20412414523193154f : 1.f;
    int cc = tid >> 2, kp = (tid & 3)*16;
    unsigned ow[8];
    #pragma unroll
    for (int j = 0; j < 8; ++j)
      ow[j] = pk_bf(t[kp + 2*j][cc]*scale, t[kp + 2*j + 1][cc]*scale);
    unsigned short* dst = wBall + ((size_t)(mat*384 + c0 + cc)*384 + k0 + kp);
    *(uint4*)dst       = make_uint4(ow[0], ow[1], ow[2], ow[3]);
    *(uint4*)(dst + 8) = make_uint4(ow[4], ow[5], ow[6], ow[7]);
  } else if (bid < 436){
    int r = (bid - 180)*4 + (tid >> 6), l = tid & 63;
    const float* ap = a + (size_t)r*384;
    float x[6]; float s = 0.f, sq = 0.f;
    #pragma unroll
    for (int i = 0; i < 6; ++i){ x[i] = ap[i*64 + l]; s += x[i]; sq += x[i]*x[i]; }
    #pragma unroll
    for (int off = 32; off; off >>= 1){ s += __shfl_xor(s, off); sq += __shfl_xor(sq, off); }
    float mu = s*(1.f/384.f);
    float var = sq*(1.f/384.f) - mu*mu;
    float rs = rsqrtf(var + 1e-5f);
    #pragma unroll
    for (int i = 0; i < 6; ++i){ int c = i*64 + l; a_lnB[(size_t)r*384 + c] = f2bf((x[i]-mu)*rs*ln_a_w[c] + ln_a_b[c]); }
  } else if (bid == 436){
    if (tid < 128){
      float lw = lnzw[tid];
      #pragma unroll
      for (int h = 0; h < 16; ++h) wwB[tid*16 + h] = f2bf(lw * w_z[tid*16 + h]);
    }
    if (tid < 16){
      float T = 0.f, U = 0.f;
      for (int c = 0; c < 128; ++c){ T += lnzw[c]*w_z[c*16 + tid]; U += lnzb[c]*w_z[c*16 + tid]; }
      TU[tid] = T; TU[16 + tid] = U;
    }
  } else {
    int t = (bid - 437)*256 + tid;       // 0..49151
    uint4 zv = make_uint4(0,0,0,0);
    if (t < 16384)      *(uint4*)(qTp + (size_t)t*32 + 24) = zv;
    else if (t < 32768) *(uint4*)(kTp + (size_t)(t - 16384)*32 + 24) = zv;
    else {
      int t2 = t - 32768;                 // 0..16383
      int h = t2 >> 10, w = t2 & 1023;
      *(uint4*)(vTt + ((size_t)h*32 + 24)*1024 + (size_t)w*8) = zv;
    }
  }
}

// ---- fused QKVG MFMA: emits qTp/kTp bf16 [h][1024][32], vTt bf16 [h][32][1024], g f32 ----
__global__ __launch_bounds__(256) void qkvg_kernel(const unsigned short* __restrict__ AB,
                                                   const unsigned short* __restrict__ wBt,
                                                   const float* __restrict__ bg,
                                                   unsigned short* __restrict__ qTp, unsigned short* __restrict__ kTp,
                                                   unsigned short* __restrict__ vTt, float* __restrict__ g){
  __shared__ short Al[64*8*8];
  __shared__ short Bl[64*8*8];
  int tid = threadIdx.x;
  int wave = tid >> 6, lane = tid & 63, l15 = lane & 15, sub = lane >> 4;
  int n0 = blockIdx.x*64, m0 = blockIdx.y*64;
  f32x4 acc[4];
  #pragma unroll
  for (int c = 0; c < 4; ++c) acc[c] = (f32x4){0.f,0.f,0.f,0.f};
  const s16x8* Ag = (const s16x8*)AB;
  const s16x8* Bg = (const s16x8*)wBt;
  s16x8* Al8 = (s16x8*)Al; s16x8* Bl8 = (s16x8*)Bl;
  for (int ks = 0; ks < 6; ++ks){
    int k0u = ks*8;
    #pragma unroll
    for (int j = 0; j < 2; ++j){
      int idx = tid*2 + j;
      int row = idx >> 3, u = idx & 7;
      Al8[row*8 + (u ^ (row & 7))] = Ag[(size_t)(m0 + row)*48 + k0u + u];
      Bl8[row*8 + (u ^ (row & 7))] = Bg[(size_t)(n0 + row)*48 + k0u + u];
    }
    __syncthreads();
    #pragma unroll
    for (int kk = 0; kk < 2; ++kk){
      int arow = wave*16 + l15;
      s16x8 af = Al8[arow*8 + ((kk*4 + sub) ^ (arow & 7))];
      #pragma unroll
      for (int c = 0; c < 4; ++c){
        int brow = c*16 + l15;
        s16x8 bf = Bl8[brow*8 + ((kk*4 + sub) ^ (brow & 7))];
        acc[c] = __builtin_amdgcn_mfma_f32_16x16x32_bf16(af, bf, acc[c], 0, 0, 0);
      }
    }
    __syncthreads();
  }
  int which = blockIdx.x / 6;
  int cb = n0 - which*384;
  if (which == 3){
    #pragma unroll
    for (int c = 0; c < 4; ++c){
      int col = cb + c*16 + l15;
      #pragma unroll
      for (int r = 0; r < 4; ++r){
        int row = m0 + wave*16 + sub*4 + r;
        float t = acc[c][r] + bg[col];
        g[(size_t)row*384 + col] = 1.f/(1.f + __expf(-t));
      }
    }
  } else if (which == 2){
    #pragma unroll
    for (int c = 0; c < 4; ++c){
      int col = cb + c*16 + l15;
      int h = col/24, d = col - h*24;
      unsigned p0 = pk_bf(acc[c][0], acc[c][1]);
      unsigned p1 = pk_bf(acc[c][2], acc[c][3]);
      size_t base = ((size_t)h*32 + d)*1024 + (size_t)(m0 + wave*16 + sub*4);
      *(uint2*)(vTt + base) = make_uint2(p0, p1);
    }
  } else {
    unsigned short* dst = which == 0 ? qTp : kTp;
    #pragma unroll
    for (int c = 0; c < 4; ++c){
      int col = cb + c*16 + l15;
      int h = col/24, d = col - h*24;
      #pragma unroll
      for (int r = 0; r < 4; ++r){
        int row = m0 + wave*16 + sub*4 + r;
        dst[((size_t)(h << 10) + row)*32 + d] = f2bf(acc[c][r]);
      }
    }
  }
}

// ---- z bias v7: 16q x 4k tiles; swapped-attn pbM layout; coalesced uint2 stores ----
// tile row r (0..63) -> pair (q0 + (r>>2))*1024 + k0 + (r&3)
__global__ __launch_bounds__(256) void zbias_kernel(const float* __restrict__ z, const unsigned short* __restrict__ wwB,
                                                    const float* __restrict__ TU, const float* __restrict__ mask,
                                                    unsigned short* __restrict__ pbM){
  __shared__ float sums[2][64];
  __shared__ float sqs[2][64];
  __shared__ float accT[2][64][17];
  int tid = threadIdx.x;
  int wave = tid >> 6, lane = tid & 63;
  int h = lane & 15, sub = lane >> 4;
  s16x8 bfr[4];
  #pragma unroll
  for (int kc = 0; kc < 4; ++kc)
    #pragma unroll
    for (int j = 0; j < 8; ++j) bfr[kc][j] = (short)wwB[(kc*32 + sub*8 + j)*16 + h];
  s16x8 ones1;
  #pragma unroll
  for (int j = 0; j < 8; ++j) ones1[j] = (h == 0) ? (short)0x3F80 : (short)0;
  int eh = tid >> 4, eq = tid & 15;
  float Te = TU[eh], Ue = TU[16 + eh];
  uint2* pbU = (uint2*)pbM;
  int row_l = wave*16 + h;
  for (int it = 0; it < 4; ++it){
    int bb = it & 1;
    int tile = blockIdx.x + it*4096;
    int qt = tile >> 8, kt = tile & 255;
    int q0 = qt*16, k0 = kt*4;
    const float* zrow = z + ((size_t)(q0 + (row_l >> 2))*1024 + k0 + (row_l & 3))*128;
    f32x4 acc  = {0.f, 0.f, 0.f, 0.f};
    f32x4 accS = {0.f, 0.f, 0.f, 0.f};
    f32x4 accG = {0.f, 0.f, 0.f, 0.f};
    #pragma unroll
    for (int kc = 0; kc < 4; ++kc){
      f32x4 v0 = *(const f32x4*)(zrow + kc*32 + sub*8);
      f32x4 v1 = *(const f32x4*)(zrow + kc*32 + sub*8 + 4);
      union { unsigned u[4]; s16x8 s; } cv;
      cv.u[0] = pk_bf(v0.x, v0.y); cv.u[1] = pk_bf(v0.z, v0.w);
      cv.u[2] = pk_bf(v1.x, v1.y); cv.u[3] = pk_bf(v1.z, v1.w);
      s16x8 af = cv.s;
      acc  = __builtin_amdgcn_mfma_f32_16x16x32_bf16(af, bfr[kc], acc, 0, 0, 0);
      accS = __builtin_amdgcn_mfma_f32_16x16x32_bf16(af, ones1, accS, 0, 0, 0);
      accG = __builtin_amdgcn_mfma_f32_16x16x32_bf16(af, af, accG, 0, 0, 0);
    }
    #pragma unroll
    for (int r = 0; r < 4; ++r) accT[bb][wave*16 + sub*4 + r][h] = acc[r];
    if (h == 0){
      #pragma unroll
      for (int r = 0; r < 4; ++r) sums[bb][wave*16 + sub*4 + r] = accS[r];
    }
    if (sub == (h >> 2)){
      int r = h & 3;
      float vq = r == 0 ? accG[0] : r == 1 ? accG[1] : r == 2 ? accG[2] : accG[3];
      sqs[bb][wave*16 + h] = vq;
    }
    __syncthreads();
    // epilogue: thread (eh, eq) -> q = q0+eq, k = k0..k0+3, h = eh
    float4 mk = *(const float4*)(mask + k0);
    float mbv0 = 1e9f*(mk.x - 1.f), mbv1 = 1e9f*(mk.y - 1.f);
    float mbv2 = 1e9f*(mk.z - 1.f), mbv3 = 1e9f*(mk.w - 1.f);
    unsigned short pv[4];
    #pragma unroll
    for (int kl = 0; kl < 4; ++kl){
      int row = eq*4 + kl;
      float mu = sums[bb][row]*(1.f/128.f);
      float var = sqs[bb][row]*(1.f/128.f) - mu*mu;
      float rs = rsqrtf(var + 1e-5f);
      float mb = kl == 0 ? mbv0 : kl == 1 ? mbv1 : kl == 2 ? mbv2 : mbv3;
      pv[kl] = f2bf(rs*(accT[bb][row][eh] - mu*Te) + Ue + mb);
    }
    int q = q0 + eq;
    int qb = q >> 6, qg = (q >> 4) & 3, l15q = q & 15;
    int kkt = k0 >> 6, c = (k0 >> 4) & 3, subk = (k0 >> 2) & 3;
    pbU[((((size_t)(eh*16 + qb)*16 + kkt)*4 + qg)*4 + c)*64 + subk*16 + l15q] =
        make_uint2(((unsigned)pv[1] << 16) | pv[0], ((unsigned)pv[3] << 16) | pv[2]);
  }
}

// ---- attn v11: swapped-operand MFMA flash (T12); scalar m/lsum; b64 P writes ----
__global__ __launch_bounds__(512) void attn_kernel(const unsigned short* __restrict__ qTp, const unsigned short* __restrict__ kTp,
                                                   const unsigned short* __restrict__ vTt, const unsigned short* __restrict__ pbM,
                                                   const float* __restrict__ g, unsigned short* __restrict__ ogB){
  __shared__ float lds[8192];
  int tid = threadIdx.x;
  int wave = tid >> 6, lane = tid & 63, l15 = lane & 15, sub = lane >> 4;
  int qb32 = blockIdx.x, h = blockIdx.y;
  int qg_l = wave & 1, kkq = wave >> 1;
  int qrow = qb32*32 + qg_l*16 + l15;
  int qb64 = qb32 >> 1, qg4 = (qb32 & 1)*2 + qg_l;
  const unsigned short* kBase = kTp + ((size_t)(h << 10))*32;
  const unsigned short* vBase = vTt + (size_t)h*32*1024;
  const uint2* pbU = (const uint2*)pbM;
  // prefetch ALL pb tiles: pvAll[t][c] for (q=l15, kk=c*16+sub*4+r) of tile kkt=kkq*4+t
  uint2 pvAll[4][4];
  #pragma unroll
  for (int t = 0; t < 4; ++t){
    size_t tb = ((((size_t)(h*16 + qb64)*16 + (kkq*4 + t))*4 + qg4)*4)*64 + lane;
    pvAll[t][0] = pbU[tb +   0];
    pvAll[t][1] = pbU[tb +  64];
    pvAll[t][2] = pbU[tb + 128];
    pvAll[t][3] = pbU[tb + 192];
  }
  s16x8 qf = *(const s16x8*)(qTp + ((size_t)(h << 10) + qrow)*32 + sub*8);
  f32x4 o0 = {0.f,0.f,0.f,0.f}, o1 = {0.f,0.f,0.f,0.f};
  float m = -1e30f, lsum = 0.f;
  char* Pb = (char*)(lds + wave*1024);
  s16x8 kfA0, kfA1, kfA2, kfA3;
  {
    int kk0 = (kkq*4)*64;
    kfA0 = *(const s16x8*)(kBase + (size_t)(kk0 +  0 + l15)*32 + sub*8);
    kfA1 = *(const s16x8*)(kBase + (size_t)(kk0 + 16 + l15)*32 + sub*8);
    kfA2 = *(const s16x8*)(kBase + (size_t)(kk0 + 32 + l15)*32 + sub*8);
    kfA3 = *(const s16x8*)(kBase + (size_t)(kk0 + 48 + l15)*32 + sub*8);
  }
  #pragma unroll
  for (int t = 0; t < 4; ++t){
    int kk0 = (kkq*4 + t)*64;
    f32x4 s[4];
    // SWAPPED: A=K, B=Q -> s[c][r] = S[kk = kk0+c*16+sub*4+r][q = l15-row of this block]
    s[0] = __builtin_amdgcn_mfma_f32_16x16x32_bf16(kfA0, qf, (f32x4){0.f,0.f,0.f,0.f}, 0, 0, 0);
    s[1] = __builtin_amdgcn_mfma_f32_16x16x32_bf16(kfA1, qf, (f32x4){0.f,0.f,0.f,0.f}, 0, 0, 0);
    s[2] = __builtin_amdgcn_mfma_f32_16x16x32_bf16(kfA2, qf, (f32x4){0.f,0.f,0.f,0.f}, 0, 0, 0);
    s[3] = __builtin_amdgcn_mfma_f32_16x16x32_bf16(kfA3, qf, (f32x4){0.f,0.f,0.f,0.f}, 0, 0, 0);
    if (t < 3){
      int nk = kk0 + 64;
      kfA0 = *(const s16x8*)(kBase + (size_t)(nk +  0 + l15)*32 + sub*8);
      kfA1 = *(const s16x8*)(kBase + (size_t)(nk + 16 + l15)*32 + sub*8);
      kfA2 = *(const s16x8*)(kBase + (size_t)(nk + 32 + l15)*32 + sub*8);
      kfA3 = *(const s16x8*)(kBase + (size_t)(nk + 48 + l15)*32 + sub*8);
    }
    #pragma unroll
    for (int c = 0; c < 4; ++c){
      s[c][0] += bf2f((unsigned short)(pvAll[t][c].x & 0xffff));
      s[c][1] += bf2f((unsigned short)(pvAll[t][c].x >> 16));
      s[c][2] += bf2f((unsigned short)(pvAll[t][c].y & 0xffff));
      s[c][3] += bf2f((unsigned short)(pvAll[t][c].y >> 16));
    }
    // softmax over kk for q = l15 (lane-local 16 + 2 shuffle stages across sub)
    float p01 = fmaxf(fmaxf(s[0][0], s[0][1]), fmaxf(s[0][2], s[0][3]));
    float p23 = fmaxf(fmaxf(s[1][0], s[1][1]), fmaxf(s[1][2], s[1][3]));
    float p45 = fmaxf(fmaxf(s[2][0], s[2][1]), fmaxf(s[2][2], s[2][3]));
    float p67 = fmaxf(fmaxf(s[3][0], s[3][1]), fmaxf(s[3][2], s[3][3]));
    float pm = fmaxf(fmaxf(p01, p23), fmaxf(p45, p67));
    pm = fmaxf(pm, __shfl_xor(pm, 16));
    pm = fmaxf(pm, __shfl_xor(pm, 32));
    float mn = fmaxf(m, pm);
    float corrL = __expf(m - mn);
    m = mn;
    float ps = 0.f;
    #pragma unroll
    for (int c = 0; c < 4; ++c){
      #pragma unroll
      for (int r = 0; r < 4; ++r){ s[c][r] = __expf(s[c][r] - mn); ps += s[c][r]; }
    }
    ps += __shfl_xor(ps, 16);
    ps += __shfl_xor(ps, 32);
    lsum = lsum*corrL + ps;
    // rescale O (q = sub*4+r) with corr from lane l15 = sub*4+r
    float cr0 = __shfl(corrL, sub*4 + 0);
    float cr1 = __shfl(corrL, sub*4 + 1);
    float cr2 = __shfl(corrL, sub*4 + 2);
    float cr3 = __shfl(corrL, sub*4 + 3);
    o0[0] *= cr0; o0[1] *= cr1; o0[2] *= cr2; o0[3] *= cr3;
    o1[0] *= cr0; o1[1] *= cr1; o1[2] *= cr2; o1[3] *= cr3;
    // P -> LDS: layout [q=l15][kk], write uint2 (4 bf16, kk=c*16+sub*4+0..3) per c
    #pragma unroll
    for (int c = 0; c < 4; ++c){
      unsigned u0 = pk_bf(s[c][0], s[c][1]);
      unsigned u1 = pk_bf(s[c][2], s[c][3]);
      int byte = (l15*128 + c*32 + sub*8) ^ ((l15 & 7) << 4);
      *(uint2*)(Pb + byte) = make_uint2(u0, u1);
    }
    // PV: A = P[q=l15][k], B = V^T — unchanged
    #pragma unroll
    for (int kh = 0; kh < 2; ++kh){
      int byteA = (l15*128 + kh*64 + sub*16) ^ ((l15 & 7) << 4);
      s16x8 pa = *(const s16x8*)(Pb + byteA);
      s16x8 vb0 = *(const s16x8*)(vBase + (size_t)l15*1024 + kk0 + kh*32 + sub*8);
      s16x8 vb1 = *(const s16x8*)(vBase + (size_t)(16 + l15)*1024 + kk0 + kh*32 + sub*8);
      o0 = __builtin_amdgcn_mfma_f32_16x16x32_bf16(pa, vb0, o0, 0, 0, 0);
      o1 = __builtin_amdgcn_mfma_f32_16x16x32_bf16(pa, vb1, o1, 0, 0, 0);
    }
  }
  // realign m/lsum (q=l15) to o-layout (q=sub*4+r)
  float mr[4], lr[4];
  #pragma unroll
  for (int r = 0; r < 4; ++r){
    mr[r] = __shfl(m, sub*4 + r);
    lr[r] = __shfl(lsum, sub*4 + r);
  }
  {
    float* cw = lds + wave*1024 + lane*16;
    cw[0] = o0[0]; cw[1] = o0[1]; cw[2] = o0[2]; cw[3] = o0[3];
    cw[4] = o1[0]; cw[5] = o1[1]; cw[6] = o1[2]; cw[7] = o1[3];
    cw[8] = mr[0]; cw[9] = mr[1]; cw[10] = mr[2]; cw[11] = mr[3];
    cw[12] = lr[0]; cw[13] = lr[1]; cw[14] = lr[2]; cw[15] = lr[3];
  }
  __syncthreads();
  if (kkq == 0){
    #pragma unroll
    for (int k2 = 1; k2 < 4; ++k2){
      const float* c2 = lds + (size_t)(k2*2 + qg_l)*1024 + lane*16;
      #pragma unroll
      for (int r = 0; r < 4; ++r){
        float m2 = c2[8 + r], l2 = c2[12 + r];
        float nm = fmaxf(mr[r], m2);
        float f1 = __expf(mr[r] - nm), f2 = __expf(m2 - nm);
        lr[r] = lr[r]*f1 + l2*f2;
        o0[r] = o0[r]*f1 + c2[r]*f2;
        o1[r] = o1[r]*f1 + c2[4 + r]*f2;
        mr[r] = nm;
      }
    }
    #pragma unroll
    for (int r = 0; r < 4; ++r){
      float inv = 1.f/lr[r];
      int q = qb32*32 + qg_l*16 + sub*4 + r;
      size_t base = (size_t)q*384 + h*24;
      ogB[base + l15] = f2bf(g[base + l15]*o0[r]*inv);
      if (l15 < 8) ogB[base + 16 + l15] = f2bf(g[base + 16 + l15]*o1[r]*inv);
    }
  }
}

// ---- final projection: ogB[1024x384]bf16 @ wo^T bf16 via MFMA, + bo ----
__global__ __launch_bounds__(256) void gemm_out(const unsigned short* __restrict__ AB,
                                                const unsigned short* __restrict__ wBo,
                                                const float* __restrict__ bo, float* __restrict__ dst){
  __shared__ short Al[64*8*8];
  __shared__ short Bl[64*8*8];
  int tid = threadIdx.x;
  int wave = tid >> 6, lane = tid & 63, l15 = lane & 15, sub = lane >> 4;
  int n0 = blockIdx.x*64, m0 = blockIdx.y*64;
  f32x4 acc[4];
  #pragma unroll
  for (int c = 0; c < 4; ++c) acc[c] = (f32x4){0.f,0.f,0.f,0.f};
  const s16x8* Ag = (const s16x8*)AB;
  const s16x8* Bg = (const s16x8*)wBo;
  s16x8* Al8 = (s16x8*)Al; s16x8* Bl8 = (s16x8*)Bl;
  for (int ks = 0; ks < 6; ++ks){
    int k0u = ks*8;
    #pragma unroll
    for (int j = 0; j < 2; ++j){
      int idx = tid*2 + j;
      int row = idx >> 3, u = idx & 7;
      Al8[row*8 + (u ^ (row & 7))] = Ag[(size_t)(m0 + row)*48 + k0u + u];
      Bl8[row*8 + (u ^ (row & 7))] = Bg[(size_t)(n0 + row)*48 + k0u + u];
    }
    __syncthreads();
    #pragma unroll
    for (int kk = 0; kk < 2; ++kk){
      int arow = wave*16 + l15;
      s16x8 af = Al8[arow*8 + ((kk*4 + sub) ^ (arow & 7))];
      #pragma unroll
      for (int c = 0; c < 4; ++c){
        int brow = c*16 + l15;
        s16x8 bf = Bl8[brow*8 + ((kk*4 + sub) ^ (brow & 7))];
        acc[c] = __builtin_amdgcn_mfma_f32_16x16x32_bf16(af, bf, acc[c], 0, 0, 0);
      }
    }
    __syncthreads();
  }
  #pragma unroll
  for (int c = 0; c < 4; ++c){
    int col = n0 + c*16 + l15;
    float b = bo[col];
    #pragma unroll
    for (int r = 0; r < 4; ++r){
      int row = m0 + wave*16 + sub*4 + r;
      dst[(size_t)row*384 + col] = acc[c][r] + b;
    }
  }
}

extern "C" void kernel_launch(void* const* d_in, const int* in_sizes, int n_in,
                              void* d_out, int out_size, void* d_ws, size_t ws_size,
                              hipStream_t stream){
  const float* a      = (const float*)d_in[0];
  const float* z      = (const float*)d_in[1];
  const float* mask   = (const float*)d_in[2];
  const float* ln_a_w = (const float*)d_in[3];
  const float* ln_a_b = (const float*)d_in[4];
  const float* ln_z_w = (const float*)d_in[5];
  const float* ln_z_b = (const float*)d_in[6];
  const float* w_z    = (const float*)d_in[7];
  const float* wq     = (const float*)d_in[8];
  const float* wk     = (const float*)d_in[9];
  const float* wv     = (const float*)d_in[10];
  const float* wg     = (const float*)d_in[11];
  const float* bg     = (const float*)d_in[12];
  const float* wo     = (const float*)d_in[13];
  const float* bo     = (const float*)d_in[14];

  char* ws = (char*)d_ws;
  unsigned short* a_lnB = (unsigned short*)(ws + ((size_t)0u));
  unsigned short* wBall = (unsigned short*)(ws + ((size_t)1u << 20));
  unsigned short* qTp   = (unsigned short*)(ws + ((size_t)4u << 20));
  unsigned short* kTp   = (unsigned short*)(ws + ((size_t)6u << 20));
  unsigned short* vTt   = (unsigned short*)(ws + ((size_t)8u << 20));
  float* g    = (float*)(ws + ((size_t)10u << 20));
  unsigned short* ogB = (unsigned short*)(ws + ((size_t)12u << 20));
  unsigned short* wwB = (unsigned short*)(ws + ((size_t)14u << 20));
  float* TU   = (float*)(ws + ((size_t)14u << 20) + 8192);
  unsigned short* pbM = (unsigned short*)(ws + ((size_t)24u << 20));

  hipLaunchKernelGGL(prep_kernel, dim3(629), dim3(256), 0, stream, a, ln_a_w, ln_a_b,
                     ln_z_w, ln_z_b, w_z, wq, wk, wv, wg, wo, a_lnB, wBall, wwB, TU, qTp, kTp, vTt);
  hipLaunchKernelGGL(qkvg_kernel, dim3(24,16), dim3(256), 0, stream, a_lnB, wBall, bg, qTp, kTp, vTt, g);
  hipLaunchKernelGGL(zbias_kernel, dim3(4096), dim3(256), 0, stream, z, wwB, TU, mask, pbM);
  hipLaunchKernelGGL(attn_kernel, dim3(32,16), dim3(512), 0, stream, qTp, kTp, vTt, pbM, g, ogB);
  hipLaunchKernelGGL(gemm_out, dim3(6,16), dim3(256), 0, stream, ogB, wBall + (size_t)4*384*384, bo, (float*)d_out);
}

// Round 18
// 155.880 us; speedup vs baseline: 7.8959x; 1.0058x over previous
//
#include <hip/hip_runtime.h>
#include <hip/hip_bf16.h>

typedef float f32x4 __attribute__((ext_vector_type(4)));
typedef short s16x8 __attribute__((ext_vector_type(8)));

__device__ __forceinline__ unsigned short f2bf(float x){
  unsigned u = __float_as_uint(x);
  u += 0x7fffu + ((u >> 16) & 1u);
  return (unsigned short)(u >> 16);
}
__device__ __forceinline__ float bf2f(unsigned short h){
  return __uint_as_float(((unsigned)h) << 16);
}
__device__ __forceinline__ unsigned pk_bf(float a, float b){
  __hip_bfloat162 t = __float22bfloat162_rn(make_float2(a, b));
  return *reinterpret_cast<unsigned*>(&t);
}

// ---- prep: weight transpose->bf16 (0..179), ln_a (180..435), setup (436), zero-pads (437..628) ----
__global__ __launch_bounds__(256) void prep_kernel(const float* __restrict__ a, const float* __restrict__ ln_a_w,
                             const float* __restrict__ ln_a_b, const float* __restrict__ lnzw,
                             const float* __restrict__ lnzb, const float* __restrict__ w_z,
                             const float* __restrict__ wq, const float* __restrict__ wk,
                             const float* __restrict__ wv, const float* __restrict__ wg,
                             const float* __restrict__ wo,
                             unsigned short* __restrict__ a_lnB, unsigned short* __restrict__ wBall,
                             unsigned short* __restrict__ wwB, float* __restrict__ TU,
                             unsigned short* __restrict__ qTp, unsigned short* __restrict__ kTp,
                             unsigned short* __restrict__ vTt){
  int bid = blockIdx.x, tid = threadIdx.x;
  if (bid < 180){
    __shared__ float t[64][65];
    int mat = bid/36, tt = bid - mat*36;
    int c0 = (tt % 6)*64, k0 = (tt / 6)*64;
    const float* src = mat == 0 ? wq : mat == 1 ? wk : mat == 2 ? wv : mat == 3 ? wg : wo;
    int r = tid >> 4, c4 = (tid & 15)*4;
    #pragma unroll
    for (int rr = 0; rr < 4; ++rr){
      float4 v = *(const float4*)(src + (size_t)(k0 + r + rr*16)*384 + c0 + c4);
      t[r + rr*16][c4+0] = v.x; t[r + rr*16][c4+1] = v.y;
      t[r + rr*16][c4+2] = v.z; t[r + rr*16][c4+3] = v.w;
    }
    __syncthreads();
    float scale = (mat == 0) ? 0.20412414523193154f : 1.f;
    int cc = tid >> 2, kp = (tid & 3)*16;
    unsigned ow[8];
    #pragma unroll
    for (int j = 0; j < 8; ++j)
      ow[j] = pk_bf(t[kp + 2*j][cc]*scale, t[kp + 2*j + 1][cc]*scale);
    unsigned short* dst = wBall + ((size_t)(mat*384 + c0 + cc)*384 + k0 + kp);
    *(uint4*)dst       = make_uint4(ow[0], ow[1], ow[2], ow[3]);
    *(uint4*)(dst + 8) = make_uint4(ow[4], ow[5], ow[6], ow[7]);
  } else if (bid < 436){
    int r = (bid - 180)*4 + (tid >> 6), l = tid & 63;
    const float* ap = a + (size_t)r*384;
    float x[6]; float s = 0.f, sq = 0.f;
    #pragma unroll
    for (int i = 0; i < 6; ++i){ x[i] = ap[i*64 + l]; s += x[i]; sq += x[i]*x[i]; }
    #pragma unroll
    for (int off = 32; off; off >>= 1){ s += __shfl_xor(s, off); sq += __shfl_xor(sq, off); }
    float mu = s*(1.f/384.f);
    float var = sq*(1.f/384.f) - mu*mu;
    float rs = rsqrtf(var + 1e-5f);
    #pragma unroll
    for (int i = 0; i < 6; ++i){ int c = i*64 + l; a_lnB[(size_t)r*384 + c] = f2bf((x[i]-mu)*rs*ln_a_w[c] + ln_a_b[c]); }
  } else if (bid == 436){
    if (tid < 128){
      float lw = lnzw[tid];
      #pragma unroll
      for (int h = 0; h < 16; ++h) wwB[tid*16 + h] = f2bf(lw * w_z[tid*16 + h]);
    }
    if (tid < 16){
      float T = 0.f, U = 0.f;
      for (int c = 0; c < 128; ++c){ T += lnzw[c]*w_z[c*16 + tid]; U += lnzb[c]*w_z[c*16 + tid]; }
      TU[tid] = T; TU[16 + tid] = U;
    }
  } else {
    int t = (bid - 437)*256 + tid;       // 0..49151
    uint4 zv = make_uint4(0,0,0,0);
    if (t < 16384)      *(uint4*)(qTp + (size_t)t*32 + 24) = zv;
    else if (t < 32768) *(uint4*)(kTp + (size_t)(t - 16384)*32 + 24) = zv;
    else {
      int t2 = t - 32768;                 // 0..16383
      int h = t2 >> 10, w = t2 & 1023;
      *(uint4*)(vTt + ((size_t)h*32 + 24)*1024 + (size_t)w*8) = zv;
    }
  }
}

// ---- fused QKVG MFMA: emits qTp/kTp bf16 [h][1024][32], vTt bf16 [h][32][1024], g f32 ----
__global__ __launch_bounds__(256) void qkvg_kernel(const unsigned short* __restrict__ AB,
                                                   const unsigned short* __restrict__ wBt,
                                                   const float* __restrict__ bg,
                                                   unsigned short* __restrict__ qTp, unsigned short* __restrict__ kTp,
                                                   unsigned short* __restrict__ vTt, float* __restrict__ g){
  __shared__ short Al[64*8*8];
  __shared__ short Bl[64*8*8];
  int tid = threadIdx.x;
  int wave = tid >> 6, lane = tid & 63, l15 = lane & 15, sub = lane >> 4;
  int n0 = blockIdx.x*64, m0 = blockIdx.y*64;
  f32x4 acc[4];
  #pragma unroll
  for (int c = 0; c < 4; ++c) acc[c] = (f32x4){0.f,0.f,0.f,0.f};
  const s16x8* Ag = (const s16x8*)AB;
  const s16x8* Bg = (const s16x8*)wBt;
  s16x8* Al8 = (s16x8*)Al; s16x8* Bl8 = (s16x8*)Bl;
  for (int ks = 0; ks < 6; ++ks){
    int k0u = ks*8;
    #pragma unroll
    for (int j = 0; j < 2; ++j){
      int idx = tid*2 + j;
      int row = idx >> 3, u = idx & 7;
      Al8[row*8 + (u ^ (row & 7))] = Ag[(size_t)(m0 + row)*48 + k0u + u];
      Bl8[row*8 + (u ^ (row & 7))] = Bg[(size_t)(n0 + row)*48 + k0u + u];
    }
    __syncthreads();
    #pragma unroll
    for (int kk = 0; kk < 2; ++kk){
      int arow = wave*16 + l15;
      s16x8 af = Al8[arow*8 + ((kk*4 + sub) ^ (arow & 7))];
      #pragma unroll
      for (int c = 0; c < 4; ++c){
        int brow = c*16 + l15;
        s16x8 bf = Bl8[brow*8 + ((kk*4 + sub) ^ (brow & 7))];
        acc[c] = __builtin_amdgcn_mfma_f32_16x16x32_bf16(af, bf, acc[c], 0, 0, 0);
      }
    }
    __syncthreads();
  }
  int which = blockIdx.x / 6;
  int cb = n0 - which*384;
  if (which == 3){
    #pragma unroll
    for (int c = 0; c < 4; ++c){
      int col = cb + c*16 + l15;
      #pragma unroll
      for (int r = 0; r < 4; ++r){
        int row = m0 + wave*16 + sub*4 + r;
        float t = acc[c][r] + bg[col];
        g[(size_t)row*384 + col] = 1.f/(1.f + __expf(-t));
      }
    }
  } else if (which == 2){
    #pragma unroll
    for (int c = 0; c < 4; ++c){
      int col = cb + c*16 + l15;
      int h = col/24, d = col - h*24;
      unsigned p0 = pk_bf(acc[c][0], acc[c][1]);
      unsigned p1 = pk_bf(acc[c][2], acc[c][3]);
      size_t base = ((size_t)h*32 + d)*1024 + (size_t)(m0 + wave*16 + sub*4);
      *(uint2*)(vTt + base) = make_uint2(p0, p1);
    }
  } else {
    unsigned short* dst = which == 0 ? qTp : kTp;
    #pragma unroll
    for (int c = 0; c < 4; ++c){
      int col = cb + c*16 + l15;
      int h = col/24, d = col - h*24;
      #pragma unroll
      for (int r = 0; r < 4; ++r){
        int row = m0 + wave*16 + sub*4 + r;
        dst[((size_t)(h << 10) + row)*32 + d] = f2bf(acc[c][r]);
      }
    }
  }
}

// ---- z bias v7: 16q x 4k tiles; swapped-attn pbM layout; coalesced uint2 stores ----
// tile row r (0..63) -> pair (q0 + (r>>2))*1024 + k0 + (r&3)
__global__ __launch_bounds__(256) void zbias_kernel(const float* __restrict__ z, const unsigned short* __restrict__ wwB,
                                                    const float* __restrict__ TU, const float* __restrict__ mask,
                                                    unsigned short* __restrict__ pbM){
  __shared__ float sums[2][64];
  __shared__ float sqs[2][64];
  __shared__ float accT[2][64][17];
  int tid = threadIdx.x;
  int wave = tid >> 6, lane = tid & 63;
  int h = lane & 15, sub = lane >> 4;
  s16x8 bfr[4];
  #pragma unroll
  for (int kc = 0; kc < 4; ++kc)
    #pragma unroll
    for (int j = 0; j < 8; ++j) bfr[kc][j] = (short)wwB[(kc*32 + sub*8 + j)*16 + h];
  s16x8 ones1;
  #pragma unroll
  for (int j = 0; j < 8; ++j) ones1[j] = (h == 0) ? (short)0x3F80 : (short)0;
  int eh = tid >> 4, eq = tid & 15;
  float Te = TU[eh], Ue = TU[16 + eh];
  uint2* pbU = (uint2*)pbM;
  int row_l = wave*16 + h;
  for (int it = 0; it < 4; ++it){
    int bb = it & 1;
    int tile = blockIdx.x + it*4096;
    int qt = tile >> 8, kt = tile & 255;
    int q0 = qt*16, k0 = kt*4;
    const float* zrow = z + ((size_t)(q0 + (row_l >> 2))*1024 + k0 + (row_l & 3))*128;
    f32x4 acc  = {0.f, 0.f, 0.f, 0.f};
    f32x4 accS = {0.f, 0.f, 0.f, 0.f};
    f32x4 accG = {0.f, 0.f, 0.f, 0.f};
    #pragma unroll
    for (int kc = 0; kc < 4; ++kc){
      f32x4 v0 = *(const f32x4*)(zrow + kc*32 + sub*8);
      f32x4 v1 = *(const f32x4*)(zrow + kc*32 + sub*8 + 4);
      union { unsigned u[4]; s16x8 s; } cv;
      cv.u[0] = pk_bf(v0.x, v0.y); cv.u[1] = pk_bf(v0.z, v0.w);
      cv.u[2] = pk_bf(v1.x, v1.y); cv.u[3] = pk_bf(v1.z, v1.w);
      s16x8 af = cv.s;
      acc  = __builtin_amdgcn_mfma_f32_16x16x32_bf16(af, bfr[kc], acc, 0, 0, 0);
      accS = __builtin_amdgcn_mfma_f32_16x16x32_bf16(af, ones1, accS, 0, 0, 0);
      accG = __builtin_amdgcn_mfma_f32_16x16x32_bf16(af, af, accG, 0, 0, 0);
    }
    #pragma unroll
    for (int r = 0; r < 4; ++r) accT[bb][wave*16 + sub*4 + r][h] = acc[r];
    if (h == 0){
      #pragma unroll
      for (int r = 0; r < 4; ++r) sums[bb][wave*16 + sub*4 + r] = accS[r];
    }
    if (sub == (h >> 2)){
      int r = h & 3;
      float vq = r == 0 ? accG[0] : r == 1 ? accG[1] : r == 2 ? accG[2] : accG[3];
      sqs[bb][wave*16 + h] = vq;
    }
    __syncthreads();
    // epilogue: thread (eh, eq) -> q = q0+eq, k = k0..k0+3, h = eh
    float4 mk = *(const float4*)(mask + k0);
    float mbv0 = 1e9f*(mk.x - 1.f), mbv1 = 1e9f*(mk.y - 1.f);
    float mbv2 = 1e9f*(mk.z - 1.f), mbv3 = 1e9f*(mk.w - 1.f);
    unsigned short pv[4];
    #pragma unroll
    for (int kl = 0; kl < 4; ++kl){
      int row = eq*4 + kl;
      float mu = sums[bb][row]*(1.f/128.f);
      float var = sqs[bb][row]*(1.f/128.f) - mu*mu;
      float rs = rsqrtf(var + 1e-5f);
      float mb = kl == 0 ? mbv0 : kl == 1 ? mbv1 : kl == 2 ? mbv2 : mbv3;
      pv[kl] = f2bf(rs*(accT[bb][row][eh] - mu*Te) + Ue + mb);
    }
    int q = q0 + eq;
    int qb = q >> 6, qg = (q >> 4) & 3, l15q = q & 15;
    int kkt = k0 >> 6, c = (k0 >> 4) & 3, subk = (k0 >> 2) & 3;
    pbU[((((size_t)(eh*16 + qb)*16 + kkt)*4 + qg)*4 + c)*64 + subk*16 + l15q] =
        make_uint2(((unsigned)pv[1] << 16) | pv[0], ((unsigned)pv[3] << 16) | pv[2]);
  }
}

// ---- attn v11: swapped-operand MFMA flash (T12); scalar m/lsum; b64 P writes ----
__global__ __launch_bounds__(512) void attn_kernel(const unsigned short* __restrict__ qTp, const unsigned short* __restrict__ kTp,
                                                   const unsigned short* __restrict__ vTt, const unsigned short* __restrict__ pbM,
                                                   const float* __restrict__ g, unsigned short* __restrict__ ogB){
  __shared__ float lds[8192];
  int tid = threadIdx.x;
  int wave = tid >> 6, lane = tid & 63, l15 = lane & 15, sub = lane >> 4;
  int qb32 = blockIdx.x, h = blockIdx.y;
  int qg_l = wave & 1, kkq = wave >> 1;
  int qrow = qb32*32 + qg_l*16 + l15;
  int qb64 = qb32 >> 1, qg4 = (qb32 & 1)*2 + qg_l;
  const unsigned short* kBase = kTp + ((size_t)(h << 10))*32;
  const unsigned short* vBase = vTt + (size_t)h*32*1024;
  const uint2* pbU = (const uint2*)pbM;
  // prefetch ALL pb tiles: pvAll[t][c] for (q=l15, kk=c*16+sub*4+r) of tile kkt=kkq*4+t
  uint2 pvAll[4][4];
  #pragma unroll
  for (int t = 0; t < 4; ++t){
    size_t tb = ((((size_t)(h*16 + qb64)*16 + (kkq*4 + t))*4 + qg4)*4)*64 + lane;
    pvAll[t][0] = pbU[tb +   0];
    pvAll[t][1] = pbU[tb +  64];
    pvAll[t][2] = pbU[tb + 128];
    pvAll[t][3] = pbU[tb + 192];
  }
  s16x8 qf = *(const s16x8*)(qTp + ((size_t)(h << 10) + qrow)*32 + sub*8);
  f32x4 o0 = {0.f,0.f,0.f,0.f}, o1 = {0.f,0.f,0.f,0.f};
  float m = -1e30f, lsum = 0.f;
  char* Pb = (char*)(lds + wave*1024);
  s16x8 kfA0, kfA1, kfA2, kfA3;
  {
    int kk0 = (kkq*4)*64;
    kfA0 = *(const s16x8*)(kBase + (size_t)(kk0 +  0 + l15)*32 + sub*8);
    kfA1 = *(const s16x8*)(kBase + (size_t)(kk0 + 16 + l15)*32 + sub*8);
    kfA2 = *(const s16x8*)(kBase + (size_t)(kk0 + 32 + l15)*32 + sub*8);
    kfA3 = *(const s16x8*)(kBase + (size_t)(kk0 + 48 + l15)*32 + sub*8);
  }
  #pragma unroll
  for (int t = 0; t < 4; ++t){
    int kk0 = (kkq*4 + t)*64;
    f32x4 s[4];
    // SWAPPED: A=K, B=Q -> s[c][r] = S[kk = kk0+c*16+sub*4+r][q = l15-row of this block]
    s[0] = __builtin_amdgcn_mfma_f32_16x16x32_bf16(kfA0, qf, (f32x4){0.f,0.f,0.f,0.f}, 0, 0, 0);
    s[1] = __builtin_amdgcn_mfma_f32_16x16x32_bf16(kfA1, qf, (f32x4){0.f,0.f,0.f,0.f}, 0, 0, 0);
    s[2] = __builtin_amdgcn_mfma_f32_16x16x32_bf16(kfA2, qf, (f32x4){0.f,0.f,0.f,0.f}, 0, 0, 0);
    s[3] = __builtin_amdgcn_mfma_f32_16x16x32_bf16(kfA3, qf, (f32x4){0.f,0.f,0.f,0.f}, 0, 0, 0);
    if (t < 3){
      int nk = kk0 + 64;
      kfA0 = *(const s16x8*)(kBase + (size_t)(nk +  0 + l15)*32 + sub*8);
      kfA1 = *(const s16x8*)(kBase + (size_t)(nk + 16 + l15)*32 + sub*8);
      kfA2 = *(const s16x8*)(kBase + (size_t)(nk + 32 + l15)*32 + sub*8);
      kfA3 = *(const s16x8*)(kBase + (size_t)(nk + 48 + l15)*32 + sub*8);
    }
    #pragma unroll
    for (int c = 0; c < 4; ++c){
      s[c][0] += bf2f((unsigned short)(pvAll[t][c].x & 0xffff));
      s[c][1] += bf2f((unsigned short)(pvAll[t][c].x >> 16));
      s[c][2] += bf2f((unsigned short)(pvAll[t][c].y & 0xffff));
      s[c][3] += bf2f((unsigned short)(pvAll[t][c].y >> 16));
    }
    // softmax over kk for q = l15 (lane-local 16 + 2 shuffle stages across sub)
    float p01 = fmaxf(fmaxf(s[0][0], s[0][1]), fmaxf(s[0][2], s[0][3]));
    float p23 = fmaxf(fmaxf(s[1][0], s[1][1]), fmaxf(s[1][2], s[1][3]));
    float p45 = fmaxf(fmaxf(s[2][0], s[2][1]), fmaxf(s[2][2], s[2][3]));
    float p67 = fmaxf(fmaxf(s[3][0], s[3][1]), fmaxf(s[3][2], s[3][3]));
    float pm = fmaxf(fmaxf(p01, p23), fmaxf(p45, p67));
    pm = fmaxf(pm, __shfl_xor(pm, 16));
    pm = fmaxf(pm, __shfl_xor(pm, 32));
    float mn = fmaxf(m, pm);
    float corrL = __expf(m - mn);
    m = mn;
    float ps = 0.f;
    #pragma unroll
    for (int c = 0; c < 4; ++c){
      #pragma unroll
      for (int r = 0; r < 4; ++r){ s[c][r] = __expf(s[c][r] - mn); ps += s[c][r]; }
    }
    ps += __shfl_xor(ps, 16);
    ps += __shfl_xor(ps, 32);
    lsum = lsum*corrL + ps;
    // rescale O (q = sub*4+r) with corr from lane l15 = sub*4+r
    float cr0 = __shfl(corrL, sub*4 + 0);
    float cr1 = __shfl(corrL, sub*4 + 1);
    float cr2 = __shfl(corrL, sub*4 + 2);
    float cr3 = __shfl(corrL, sub*4 + 3);
    o0[0] *= cr0; o0[1] *= cr1; o0[2] *= cr2; o0[3] *= cr3;
    o1[0] *= cr0; o1[1] *= cr1; o1[2] *= cr2; o1[3] *= cr3;
    // P -> LDS: layout [q=l15][kk], write uint2 (4 bf16, kk=c*16+sub*4+0..3) per c
    #pragma unroll
    for (int c = 0; c < 4; ++c){
      unsigned u0 = pk_bf(s[c][0], s[c][1]);
      unsigned u1 = pk_bf(s[c][2], s[c][3]);
      int byte = (l15*128 + c*32 + sub*8) ^ ((l15 & 7) << 4);
      *(uint2*)(Pb + byte) = make_uint2(u0, u1);
    }
    // PV: A = P[q=l15][k], B = V^T — unchanged
    #pragma unroll
    for (int kh = 0; kh < 2; ++kh){
      int byteA = (l15*128 + kh*64 + sub*16) ^ ((l15 & 7) << 4);
      s16x8 pa = *(const s16x8*)(Pb + byteA);
      s16x8 vb0 = *(const s16x8*)(vBase + (size_t)l15*1024 + kk0 + kh*32 + sub*8);
      s16x8 vb1 = *(const s16x8*)(vBase + (size_t)(16 + l15)*1024 + kk0 + kh*32 + sub*8);
      o0 = __builtin_amdgcn_mfma_f32_16x16x32_bf16(pa, vb0, o0, 0, 0, 0);
      o1 = __builtin_amdgcn_mfma_f32_16x16x32_bf16(pa, vb1, o1, 0, 0, 0);
    }
  }
  // realign m/lsum (q=l15) to o-layout (q=sub*4+r)
  float mr[4], lr[4];
  #pragma unroll
  for (int r = 0; r < 4; ++r){
    mr[r] = __shfl(m, sub*4 + r);
    lr[r] = __shfl(lsum, sub*4 + r);
  }
  {
    float* cw = lds + wave*1024 + lane*16;
    cw[0] = o0[0]; cw[1] = o0[1]; cw[2] = o0[2]; cw[3] = o0[3];
    cw[4] = o1[0]; cw[5] = o1[1]; cw[6] = o1[2]; cw[7] = o1[3];
    cw[8] = mr[0]; cw[9] = mr[1]; cw[10] = mr[2]; cw[11] = mr[3];
    cw[12] = lr[0]; cw[13] = lr[1]; cw[14] = lr[2]; cw[15] = lr[3];
  }
  __syncthreads();
  if (kkq == 0){
    #pragma unroll
    for (int k2 = 1; k2 < 4; ++k2){
      const float* c2 = lds + (size_t)(k2*2 + qg_l)*1024 + lane*16;
      #pragma unroll
      for (int r = 0; r < 4; ++r){
        float m2 = c2[8 + r], l2 = c2[12 + r];
        float nm = fmaxf(mr[r], m2);
        float f1 = __expf(mr[r] - nm), f2 = __expf(m2 - nm);
        lr[r] = lr[r]*f1 + l2*f2;
        o0[r] = o0[r]*f1 + c2[r]*f2;
        o1[r] = o1[r]*f1 + c2[4 + r]*f2;
        mr[r] = nm;
      }
    }
    #pragma unroll
    for (int r = 0; r < 4; ++r){
      float inv = 1.f/lr[r];
      int q = qb32*32 + qg_l*16 + sub*4 + r;
      size_t base = (size_t)q*384 + h*24;
      ogB[base + l15] = f2bf(g[base + l15]*o0[r]*inv);
      if (l15 < 8) ogB[base + 16 + l15] = f2bf(g[base + 16 + l15]*o1[r]*inv);
    }
  }
}

// ---- final projection: ogB[1024x384]bf16 @ wo^T bf16 via MFMA, + bo ----
__global__ __launch_bounds__(256) void gemm_out(const unsigned short* __restrict__ AB,
                                                const unsigned short* __restrict__ wBo,
                                                const float* __restrict__ bo, float* __restrict__ dst){
  __shared__ short Al[64*8*8];
  __shared__ short Bl[64*8*8];
  int tid = threadIdx.x;
  int wave = tid >> 6, lane = tid & 63, l15 = lane & 15, sub = lane >> 4;
  int n0 = blockIdx.x*64, m0 = blockIdx.y*64;
  f32x4 acc[4];
  #pragma unroll
  for (int c = 0; c < 4; ++c) acc[c] = (f32x4){0.f,0.f,0.f,0.f};
  const s16x8* Ag = (const s16x8*)AB;
  const s16x8* Bg = (const s16x8*)wBo;
  s16x8* Al8 = (s16x8*)Al; s16x8* Bl8 = (s16x8*)Bl;
  for (int ks = 0; ks < 6; ++ks){
    int k0u = ks*8;
    #pragma unroll
    for (int j = 0; j < 2; ++j){
      int idx = tid*2 + j;
      int row = idx >> 3, u = idx & 7;
      Al8[row*8 + (u ^ (row & 7))] = Ag[(size_t)(m0 + row)*48 + k0u + u];
      Bl8[row*8 + (u ^ (row & 7))] = Bg[(size_t)(n0 + row)*48 + k0u + u];
    }
    __syncthreads();
    #pragma unroll
    for (int kk = 0; kk < 2; ++kk){
      int arow = wave*16 + l15;
      s16x8 af = Al8[arow*8 + ((kk*4 + sub) ^ (arow & 7))];
      #pragma unroll
      for (int c = 0; c < 4; ++c){
        int brow = c*16 + l15;
        s16x8 bf = Bl8[brow*8 + ((kk*4 + sub) ^ (brow & 7))];
        acc[c] = __builtin_amdgcn_mfma_f32_16x16x32_bf16(af, bf, acc[c], 0, 0, 0);
      }
    }
    __syncthreads();
  }
  #pragma unroll
  for (int c = 0; c < 4; ++c){
    int col = n0 + c*16 + l15;
    float b = bo[col];
    #pragma unroll
    for (int r = 0; r < 4; ++r){
      int row = m0 + wave*16 + sub*4 + r;
      dst[(size_t)row*384 + col] = acc[c][r] + b;
    }
  }
}

extern "C" void kernel_launch(void* const* d_in, const int* in_sizes, int n_in,
                              void* d_out, int out_size, void* d_ws, size_t ws_size,
                              hipStream_t stream){
  const float* a      = (const float*)d_in[0];
  const float* z      = (const float*)d_in[1];
  const float* mask   = (const float*)d_in[2];
  const float* ln_a_w = (const float*)d_in[3];
  const float* ln_a_b = (const float*)d_in[4];
  const float* ln_z_w = (const float*)d_in[5];
  const float* ln_z_b = (const float*)d_in[6];
  const float* w_z    = (const float*)d_in[7];
  const float* wq     = (const float*)d_in[8];
  const float* wk     = (const float*)d_in[9];
  const float* wv     = (const float*)d_in[10];
  const float* wg     = (const float*)d_in[11];
  const float* bg     = (const float*)d_in[12];
  const float* wo     = (const float*)d_in[13];
  const float* bo     = (const float*)d_in[14];

  char* ws = (char*)d_ws;
  unsigned short* a_lnB = (unsigned short*)(ws + ((size_t)0u));
  unsigned short* wBall = (unsigned short*)(ws + ((size_t)1u << 20));
  unsigned short* qTp   = (unsigned short*)(ws + ((size_t)4u << 20));
  unsigned short* kTp   = (unsigned short*)(ws + ((size_t)6u << 20));
  unsigned short* vTt   = (unsigned short*)(ws + ((size_t)8u << 20));
  float* g    = (float*)(ws + ((size_t)10u << 20));
  unsigned short* ogB = (unsigned short*)(ws + ((size_t)12u << 20));
  unsigned short* wwB = (unsigned short*)(ws + ((size_t)14u << 20));
  float* TU   = (float*)(ws + ((size_t)14u << 20) + 8192);
  unsigned short* pbM = (unsigned short*)(ws + ((size_t)24u << 20));

  hipLaunchKernelGGL(prep_kernel, dim3(629), dim3(256), 0, stream, a, ln_a_w, ln_a_b,
                     ln_z_w, ln_z_b, w_z, wq, wk, wv, wg, wo, a_lnB, wBall, wwB, TU, qTp, kTp, vTt);
  hipLaunchKernelGGL(qkvg_kernel, dim3(24,16), dim3(256), 0, stream, a_lnB, wBall, bg, qTp, kTp, vTt, g);
  hipLaunchKernelGGL(zbias_kernel, dim3(4096), dim3(256), 0, stream, z, wwB, TU, mask, pbM);
  hipLaunchKernelGGL(attn_kernel, dim3(32,16), dim3(512), 0, stream, qTp, kTp, vTt, pbM, g, ogB);
  hipLaunchKernelGGL(gemm_out, dim3(6,16), dim3(256), 0, stream, ogB, wBall + (size_t)4*384*384, bo, (float*)d_out);
}